// Round 5
// baseline (1811.931 us; speedup 1.0000x reference)
//
#include <hip/hip_runtime.h>
#include <math.h>

#define T_ 512
#define B_ 64
#define V_ 50000
#define E_ 300
#define H_ 256
#define K_ 20
#define G4 1024  /* 4*H */

typedef float f4 __attribute__((ext_vector_type(4)));
typedef int v8i __attribute__((ext_vector_type(8)));
typedef short bf16x8 __attribute__((ext_vector_type(8)));
typedef _Float16 h2_t __attribute__((ext_vector_type(2)));
union U32H2 { unsigned u; h2_t h; };
__device__ __forceinline__ h2_t u2h(unsigned u) { U32H2 x; x.u = u; return x.h; }
__device__ __forceinline__ unsigned h2u(h2_t h) { U32H2 x; x.h = h; return x.u; }

__device__ __forceinline__ float sigf(float x) { return 1.f / (1.f + __expf(-x)); }
__device__ __forceinline__ float tanhfast(float x) { return 1.f - 2.f / (__expf(2.f * x) + 1.f); }

__device__ __forceinline__ unsigned char f32_e4m3(float x) {
  return (unsigned char)(__builtin_amdgcn_cvt_pk_fp8_f32(x, x, 0, false) & 0xff);
}
__device__ __forceinline__ unsigned short f32_bf16(float x) {
  union { float f; unsigned u; } v; v.f = x;
  v.u += 0x7FFFu + ((v.u >> 16) & 1u);   // RTNE
  return (unsigned short)(v.u >> 16);
}

// ---- prep: gather X=bf16(emb[inp]) (K padded to 320), pack w_ih A-frags, quantize w_hh fp8,
//      combine biases, zero out ------------------------------------------------------------
__global__ void prep_kernel(const int* __restrict__ inp,
                            const float* __restrict__ emb,
                            const float* __restrict__ w_ih, const float* __restrict__ w_hh,
                            const float* __restrict__ b_ih, const float* __restrict__ b_hh,
                            unsigned short* __restrict__ Xh, unsigned short* __restrict__ wA,
                            unsigned char* __restrict__ W8,
                            float* __restrict__ b_comb, float* __restrict__ out) {
  int tid = blockIdx.x * blockDim.x + threadIdx.x;
  int nth = gridDim.x * blockDim.x;
  // Xh[row][k], row = t*64+b, k in [0,320), zeros for k>=300
  for (int i = tid; i < 32768 * 80; i += nth) {
    int row = i / 80, c4 = i % 80, k = c4 * 4;
    ushort4 st;
    if (c4 < 75) {
      int tok = inp[row];
      float4 v = *(const float4*)(emb + (long)tok * E_ + k);
      st.x = f32_bf16(v.x); st.y = f32_bf16(v.y); st.z = f32_bf16(v.z); st.w = f32_bf16(v.w);
    } else {
      st.x = st.y = st.z = st.w = 0;
    }
    *(ushort4*)(Xh + (long)row * 320 + k) = st;
  }
  // wA[((c*4+q)*1024 + n)*8 + j] = bf16(w_ih[n][c*32 + q*8 + j]), zeros for k>=300
  for (int i = tid; i < 10 * 4 * 1024 * 8; i += nth) {
    int j = i & 7, n = (i >> 3) & 1023, q = (i >> 13) & 3, c = i >> 15;
    int k = c * 32 + q * 8 + j;
    wA[i] = (k < E_) ? f32_bf16(w_ih[n * E_ + k]) : 0;
  }
  // W8[row][k] = e4m3(w_hh[row][k] * 64)
  for (int i = tid; i < G4 * H_; i += nth) W8[i] = f32_e4m3(w_hh[i] * 64.f);
  for (int i = tid; i < G4; i += nth) b_comb[i] = b_ih[i] + b_hh[i];
  if (tid == 0) out[0] = 0.f;
}

// ---- kernel A: g_in (f16) = X @ w_ih^T + b, via bf16 MFMA ---------------------------------
// grid 4096 = 1024 m-tiles (32 rows) x 4 n-groups (256 cols). 4 waves; wave w: n-tiles 4w..4w+3.
// A = W (rows = gate units n), B = X (cols = time-batch m) -> D[n][m]; lane stores 4 n-consec f16.
__global__ __launch_bounds__(256) void kernelA(const unsigned short* __restrict__ Xh,
                                               const unsigned short* __restrict__ wA,
                                               const float* __restrict__ b_comb,
                                               _Float16* __restrict__ g_in) {
  __shared__ __align__(16) unsigned short xs[32 * 328];  // 656B rows: quarter-wave 2-way max
  int bm = blockIdx.x >> 2, bn = blockIdx.x & 3;
  int tid = threadIdx.x;
  for (int i = tid; i < 32 * 40; i += 256) {
    int r = i / 40, c = i % 40;
    *(uint4*)&xs[r * 328 + c * 8] = *(const uint4*)(Xh + (long)(bm * 32 + r) * 320 + c * 8);
  }
  __syncthreads();
  int lane = tid & 63, w = tid >> 6, col = lane & 15, quad = lane >> 4;
  int nbase = bn * 256 + w * 64;
  f4 acc[2][4];
#pragma unroll
  for (int mt = 0; mt < 2; mt++)
#pragma unroll
    for (int nt = 0; nt < 4; nt++) acc[mt][nt] = (f4){0.f, 0.f, 0.f, 0.f};
#pragma unroll 2
  for (int c = 0; c < 10; c++) {
    bf16x8 a[4], b[2];
#pragma unroll
    for (int nt = 0; nt < 4; nt++)
      a[nt] = *(const bf16x8*)(wA + (((long)c * 4 + quad) * 1024 + nbase + nt * 16 + col) * 8);
#pragma unroll
    for (int mt = 0; mt < 2; mt++)
      b[mt] = *(const bf16x8*)&xs[(mt * 16 + col) * 328 + c * 32 + quad * 8];
#pragma unroll
    for (int mt = 0; mt < 2; mt++)
#pragma unroll
      for (int nt = 0; nt < 4; nt++)
        acc[mt][nt] = __builtin_amdgcn_mfma_f32_16x16x32_bf16(a[nt], b[mt], acc[mt][nt], 0, 0, 0);
  }
#pragma unroll
  for (int mt = 0; mt < 2; mt++) {
    int m = bm * 32 + mt * 16 + col;
#pragma unroll
    for (int nt = 0; nt < 4; nt++) {
      int n = nbase + nt * 16 + quad * 4;
      f4 o = acc[mt][nt] + *(const f4*)(b_comb + n);
      h2_t p0, p1;
      p0.x = (_Float16)o.x; p0.y = (_Float16)o.y;
      p1.x = (_Float16)o.z; p1.y = (_Float16)o.w;
      uint2 st; st.x = h2u(p0); st.y = h2u(p1);
      *(uint2*)(g_in + (long)m * G4 + n) = st;
    }
  }
}

// ---- kernel B: sequential LSTM, MX-fp8 K=128 MFMA, weights pinned in AGPRs ----------------
// 16 blocks x 1024 threads. Block bb owns batches 4bb..4bb+3 (broadcast x4 into 16 cols).
// Wave w owns gate rows 16*(w+16*tau)+col, tau = i,f,g,o. 8 MFMAs/wave/step (K=128 x2 chunks).
// Lane's elementwise: r=col>>2 selects acc row -> each (batch,unit) computed exactly once.
#define WSCALE 64.f
#define HSCALE 16.f
#define DESCALE (1.f / (WSCALE * HSCALE))
#define SC1 0x7F7F7F7F  /* e8m0 exponent 127 = scale 1.0, all bytes */

__global__ __launch_bounds__(1024, 4) void kernelB(const _Float16* __restrict__ g_in,
                                                   const unsigned char* __restrict__ W8,
                                                   _Float16* __restrict__ houts) {
  int bb = blockIdx.x;
  int tid = threadIdx.x;
  int lane = tid & 63, w = tid >> 6, col = lane & 15, quad = lane >> 4;
  int cb = col & 3, r = col >> 2;

  __shared__ __align__(16) unsigned char h8[2][4 * 272];  // [buf][batch][k linear 256 + pad]
  for (int i = tid; i < 2 * 4 * 272; i += 1024) ((unsigned char*)h8)[i] = 0;

  // persistent A-frags (AGPR): wf[tau*2+c] = W8[16*(w+16*tau)+col][c*128 + quad*32 .. +31]
  v8i wf[8];
#pragma unroll
  for (int tc = 0; tc < 8; tc++) {
    int tau = tc >> 1, c = tc & 1;
    const unsigned char* rp = W8 + (unsigned)(16 * (w + 16 * tau) + col) * 256 + c * 128 + quad * 32;
    uint4 q0 = *(const uint4*)(rp);
    uint4 q1 = *(const uint4*)(rp + 16);
    wf[tc] = (v8i){(int)q0.x, (int)q0.y, (int)q0.z, (int)q0.w,
                   (int)q1.x, (int)q1.y, (int)q1.z, (int)q1.w};
  }
#pragma unroll
  for (int tc = 0; tc < 8; tc++) asm volatile("" : "+a"(wf[tc]));  // pin in AGPRs

  int myk = 16 * w + 4 * quad + r;   // this lane's hidden unit
  int batch = 4 * bb + cb;           // this lane's batch
  int myslot = cb * 272 + myk;       // linear h8 slot
  const unsigned char* bp0 = &h8[0][cb * 272 + quad * 32];
  const unsigned char* bp1 = &h8[1][cb * 272 + quad * 32];
  const _Float16* gbase = g_in + (long)batch * G4 + myk;

  float cst = 0.f;
  float gi_ = (float)gbase[0];
  float gf_ = (float)gbase[256];
  float gg_ = (float)gbase[512];
  float go_ = (float)gbase[768];

  __syncthreads();

  for (int t = 0; t < T_; t++) {
    const unsigned char* bptr = (t & 1) ? bp1 : bp0;
    v8i b0, b1;
    {
      uint4 q0 = *(const uint4*)(bptr);
      uint4 q1 = *(const uint4*)(bptr + 16);
      uint4 q2 = *(const uint4*)(bptr + 128);
      uint4 q3 = *(const uint4*)(bptr + 144);
      b0 = (v8i){(int)q0.x, (int)q0.y, (int)q0.z, (int)q0.w,
                 (int)q1.x, (int)q1.y, (int)q1.z, (int)q1.w};
      b1 = (v8i){(int)q2.x, (int)q2.y, (int)q2.z, (int)q2.w,
                 (int)q3.x, (int)q3.y, (int)q3.z, (int)q3.w};
    }
    f4 a0 = {0.f, 0.f, 0.f, 0.f}, a1 = a0, a2 = a0, a3 = a0;
    a0 = __builtin_amdgcn_mfma_scale_f32_16x16x128_f8f6f4(wf[0], b0, a0, 0, 0, 0, SC1, 0, SC1);
    a1 = __builtin_amdgcn_mfma_scale_f32_16x16x128_f8f6f4(wf[2], b0, a1, 0, 0, 0, SC1, 0, SC1);
    a2 = __builtin_amdgcn_mfma_scale_f32_16x16x128_f8f6f4(wf[4], b0, a2, 0, 0, 0, SC1, 0, SC1);
    a3 = __builtin_amdgcn_mfma_scale_f32_16x16x128_f8f6f4(wf[6], b0, a3, 0, 0, 0, SC1, 0, SC1);
    a0 = __builtin_amdgcn_mfma_scale_f32_16x16x128_f8f6f4(wf[1], b1, a0, 0, 0, 0, SC1, 0, SC1);
    a1 = __builtin_amdgcn_mfma_scale_f32_16x16x128_f8f6f4(wf[3], b1, a1, 0, 0, 0, SC1, 0, SC1);
    a2 = __builtin_amdgcn_mfma_scale_f32_16x16x128_f8f6f4(wf[5], b1, a2, 0, 0, 0, SC1, 0, SC1);
    a3 = __builtin_amdgcn_mfma_scale_f32_16x16x128_f8f6f4(wf[7], b1, a3, 0, 0, 0, SC1, 0, SC1);

    // prefetch next step's g while MFMAs drain
    int tn = (t + 1 < T_) ? (t + 1) : t;
    const _Float16* gp = gbase + (long)tn * B_ * G4;
    float ngi = (float)gp[0];
    float ngf = (float)gp[256];
    float ngg = (float)gp[512];
    float ngo = (float)gp[768];

    float gi = a0[r] * DESCALE + gi_;
    float gf = a1[r] * DESCALE + gf_;
    float gg = a2[r] * DESCALE + gg_;
    float go = a3[r] * DESCALE + go_;
    cst = sigf(gf) * cst + sigf(gi) * tanhfast(gg);
    float h = sigf(go) * tanhfast(cst);
    h8[1 - (t & 1)][myslot] = f32_e4m3(h * HSCALE);
    houts[((long)t * B_ + batch) * H_ + myk] = (_Float16)h;

    gi_ = ngi; gf_ = ngf; gg_ = ngg; go_ = ngo;
    __syncthreads();
  }
}

// ---- kernel C: emissions = houts(f16) @ W_lin^T + b_lin -----------------------------------
__global__ __launch_bounds__(256) void kernelC(const _Float16* __restrict__ houts,
                                               const float* __restrict__ W_lin,
                                               const float* __restrict__ b_lin,
                                               float* __restrict__ em) {
  __shared__ float hs[32][260];
  __shared__ float wl[20][260];
  __shared__ float bl[20];
  int bm = blockIdx.x;
  int tid = threadIdx.x;
  for (int i = tid; i < 32 * 64; i += 256) {
    int r = i >> 6, c = i & 63;
    uint2 v = *(const uint2*)(houts + ((long)(bm * 32 + r)) * H_ + c * 4);
    h2_t h0 = u2h(v.x), h1 = u2h(v.y);
    *(float4*)&hs[r][c * 4] = make_float4((float)h0.x, (float)h0.y, (float)h1.x, (float)h1.y);
  }
  for (int i = tid; i < 20 * 64; i += 256) {
    int k = i >> 6, c = i & 63;
    *(float4*)&wl[k][c * 4] = *(const float4*)(W_lin + k * H_ + c * 4);
  }
  if (tid < 20) bl[tid] = b_lin[tid];
  __syncthreads();
  for (int o = tid; o < 32 * 20; o += 256) {
    int r = o / 20, k = o % 20;
    float s = 0.f;
#pragma unroll 4
    for (int i = 0; i < H_; i++) s += hs[r][i] * wl[k][i];
    em[(long)bm * 32 * K_ + o] = s + bl[k];
  }
}

// ---- kernel D: CRF forward DP + gold score + NLL reduction --------------------------------
__global__ __launch_bounds__(64) void kernelD(const float* __restrict__ em,
                                              const int* __restrict__ labels,
                                              const float* __restrict__ start_t,
                                              const float* __restrict__ end_t,
                                              const float* __restrict__ trans,
                                              float* __restrict__ out) {
  int b = blockIdx.x;
  int k = threadIdx.x;
  __shared__ float tr[400];
  __shared__ float alpha[2][20];
  for (int i = k; i < 400; i += 64) tr[i] = trans[i];
  float score = 0.f;
  int prevtag = 0;
  if (k == 0) {
    int t0 = labels[b];
    score = start_t[t0] + em[b * K_ + t0];
    prevtag = t0;
  }
  if (k < K_) alpha[0][k] = start_t[k] + em[b * K_ + k];
  __syncthreads();
  int p = 0;
  for (int t = 1; t < T_; t++) {
    const float* emrow = em + ((long)t * B_ + b) * K_;
    if (k < K_) {
      float v[20];
      float m = -1e30f;
#pragma unroll
      for (int j = 0; j < 20; j++) {
        v[j] = alpha[p][j] + tr[j * 20 + k];
        m = fmaxf(m, v[j]);
      }
      float s = 0.f;
#pragma unroll
      for (int j = 0; j < 20; j++) s += __expf(v[j] - m);
      alpha[1 - p][k] = emrow[k] + m + __logf(s);
    }
    if (k == 0) {
      int tg = labels[t * B_ + b];
      score += tr[prevtag * 20 + tg] + emrow[tg];
      prevtag = tg;
    }
    p ^= 1;
    __syncthreads();
  }
  if (k == 0) {
    score += end_t[prevtag];
    float m = -1e30f;
    for (int j = 0; j < 20; j++) m = fmaxf(m, alpha[p][j] + end_t[j]);
    float s = 0.f;
    for (int j = 0; j < 20; j++) s += __expf(alpha[p][j] + end_t[j] - m);
    float logZ = m + __logf(s);
    atomicAdd(out, -(score - logZ));
  }
}

extern "C" void kernel_launch(void* const* d_in, const int* in_sizes, int n_in,
                              void* d_out, int out_size, void* d_ws, size_t ws_size,
                              hipStream_t stream) {
  const int*   inp     = (const int*)d_in[0];
  const int*   labels  = (const int*)d_in[1];
  const float* emb     = (const float*)d_in[2];
  const float* w_ih    = (const float*)d_in[3];
  const float* w_hh    = (const float*)d_in[4];
  const float* b_ih    = (const float*)d_in[5];
  const float* b_hh    = (const float*)d_in[6];
  const float* W_lin   = (const float*)d_in[7];
  const float* b_lin   = (const float*)d_in[8];
  const float* start_t = (const float*)d_in[9];
  const float* end_t   = (const float*)d_in[10];
  const float* trans   = (const float*)d_in[11];
  float* out = (float*)d_out;
  char* ws = (char*)d_ws;
  (void)ws_size;

  // ws layout (bytes), total ~91.6 MB:
  _Float16*       g_in   = (_Float16*)(ws);                       // 67,108,864 (T*B*1024 f16)
  unsigned short* Xh     = (unsigned short*)(ws + 67108864);      // 20,971,520 (32768x320 bf16)
  _Float16*       houts  = (_Float16*)(ws + 67108864);            // 16,777,216 — ALIASES Xh (Xh dead after kernelA)
  float*          em     = (float*)(ws + 88080384);               //  2,621,440 (T*B*K f32)
  unsigned short* wA     = (unsigned short*)(ws + 90701824);      //    655,360 (10x4x1024x8 bf16)
  unsigned char*  W8     = (unsigned char*)(ws + 91357184);       //    262,144 (1024x256 fp8)
  float*          b_comb = (float*)(ws + 91619328);               //      4,096

  prep_kernel<<<2048, 256, 0, stream>>>(inp, emb, w_ih, w_hh, b_ih, b_hh, Xh, wA, W8, b_comb, out);
  kernelA<<<4096, 256, 0, stream>>>(Xh, wA, b_comb, g_in);
  kernelB<<<16, 1024, 0, stream>>>(g_in, W8, houts);
  kernelC<<<1024, 256, 0, stream>>>(houts, W_lin, b_lin, em);
  kernelD<<<64, 64, 0, stream>>>(em, labels, start_t, end_t, trans, out);
}

// Round 6
// 1446.830 us; speedup vs baseline: 1.2523x; 1.2523x over previous
//
#include <hip/hip_runtime.h>
#include <math.h>

#define T_ 512
#define B_ 64
#define V_ 50000
#define E_ 300
#define H_ 256
#define K_ 20
#define G4 1024  /* 4*H */

typedef float f4 __attribute__((ext_vector_type(4)));
typedef short bf16x8 __attribute__((ext_vector_type(8)));
typedef _Float16 h2_t __attribute__((ext_vector_type(2)));
union U32H2 { unsigned u; h2_t h; };
__device__ __forceinline__ h2_t u2h(unsigned u) { U32H2 x; x.u = u; return x.h; }
__device__ __forceinline__ unsigned h2u(h2_t h) { U32H2 x; x.h = h; return x.u; }

__device__ __forceinline__ float sigf(float x) { return 1.f / (1.f + __expf(-x)); }
__device__ __forceinline__ float tanhfast(float x) { return 1.f - 2.f / (__expf(2.f * x) + 1.f); }

__device__ __forceinline__ unsigned char f32_e4m3(float x) {
  return (unsigned char)(__builtin_amdgcn_cvt_pk_fp8_f32(x, x, 0, false) & 0xff);
}
__device__ __forceinline__ unsigned short f32_bf16(float x) {
  union { float f; unsigned u; } v; v.f = x;
  v.u += 0x7FFFu + ((v.u >> 16) & 1u);   // RTNE
  return (unsigned short)(v.u >> 16);
}

// ---- prep: gather X=bf16(emb[inp]) (K padded to 320), pack w_ih A-frags, quantize w_hh fp8,
//      combine biases, zero out ------------------------------------------------------------
__global__ void prep_kernel(const int* __restrict__ inp,
                            const float* __restrict__ emb,
                            const float* __restrict__ w_ih, const float* __restrict__ w_hh,
                            const float* __restrict__ b_ih, const float* __restrict__ b_hh,
                            unsigned short* __restrict__ Xh, unsigned short* __restrict__ wA,
                            unsigned char* __restrict__ W8,
                            float* __restrict__ b_comb, float* __restrict__ out) {
  int tid = blockIdx.x * blockDim.x + threadIdx.x;
  int nth = gridDim.x * blockDim.x;
  // Xh[row][k], row = t*64+b, k in [0,320), zeros for k>=300
  for (int i = tid; i < 32768 * 80; i += nth) {
    int row = i / 80, c4 = i % 80, k = c4 * 4;
    ushort4 st;
    if (c4 < 75) {
      int tok = inp[row];
      float4 v = *(const float4*)(emb + (long)tok * E_ + k);
      st.x = f32_bf16(v.x); st.y = f32_bf16(v.y); st.z = f32_bf16(v.z); st.w = f32_bf16(v.w);
    } else {
      st.x = st.y = st.z = st.w = 0;
    }
    *(ushort4*)(Xh + (long)row * 320 + k) = st;
  }
  // wA[((c*4+q)*1024 + n)*8 + j] = bf16(w_ih[n][c*32 + q*8 + j]), zeros for k>=300
  for (int i = tid; i < 10 * 4 * 1024 * 8; i += nth) {
    int j = i & 7, n = (i >> 3) & 1023, q = (i >> 13) & 3, c = i >> 15;
    int k = c * 32 + q * 8 + j;
    wA[i] = (k < E_) ? f32_bf16(w_ih[n * E_ + k]) : 0;
  }
  // W8[row][k] = e4m3(w_hh[row][k] * 64)
  for (int i = tid; i < G4 * H_; i += nth) W8[i] = f32_e4m3(w_hh[i] * 64.f);
  for (int i = tid; i < G4; i += nth) b_comb[i] = b_ih[i] + b_hh[i];
  if (tid == 0) out[0] = 0.f;
}

// ---- kernel A: g_in (f16) = X @ w_ih^T + b, via bf16 MFMA ---------------------------------
__global__ __launch_bounds__(256) void kernelA(const unsigned short* __restrict__ Xh,
                                               const unsigned short* __restrict__ wA,
                                               const float* __restrict__ b_comb,
                                               _Float16* __restrict__ g_in) {
  __shared__ __align__(16) unsigned short xs[32 * 328];
  int bm = blockIdx.x >> 2, bn = blockIdx.x & 3;
  int tid = threadIdx.x;
  for (int i = tid; i < 32 * 40; i += 256) {
    int r = i / 40, c = i % 40;
    *(uint4*)&xs[r * 328 + c * 8] = *(const uint4*)(Xh + (long)(bm * 32 + r) * 320 + c * 8);
  }
  __syncthreads();
  int lane = tid & 63, w = tid >> 6, col = lane & 15, quad = lane >> 4;
  int nbase = bn * 256 + w * 64;
  f4 acc[2][4];
#pragma unroll
  for (int mt = 0; mt < 2; mt++)
#pragma unroll
    for (int nt = 0; nt < 4; nt++) acc[mt][nt] = (f4){0.f, 0.f, 0.f, 0.f};
#pragma unroll 2
  for (int c = 0; c < 10; c++) {
    bf16x8 a[4], b[2];
#pragma unroll
    for (int nt = 0; nt < 4; nt++)
      a[nt] = *(const bf16x8*)(wA + (((long)c * 4 + quad) * 1024 + nbase + nt * 16 + col) * 8);
#pragma unroll
    for (int mt = 0; mt < 2; mt++)
      b[mt] = *(const bf16x8*)&xs[(mt * 16 + col) * 328 + c * 32 + quad * 8];
#pragma unroll
    for (int mt = 0; mt < 2; mt++)
#pragma unroll
      for (int nt = 0; nt < 4; nt++)
        acc[mt][nt] = __builtin_amdgcn_mfma_f32_16x16x32_bf16(a[nt], b[mt], acc[mt][nt], 0, 0, 0);
  }
#pragma unroll
  for (int mt = 0; mt < 2; mt++) {
    int m = bm * 32 + mt * 16 + col;
#pragma unroll
    for (int nt = 0; nt < 4; nt++) {
      int n = nbase + nt * 16 + quad * 4;
      f4 o = acc[mt][nt] + *(const f4*)(b_comb + n);
      h2_t p0, p1;
      p0.x = (_Float16)o.x; p0.y = (_Float16)o.y;
      p1.x = (_Float16)o.z; p1.y = (_Float16)o.w;
      uint2 st; st.x = h2u(p0); st.y = h2u(p1);
      *(uint2*)(g_in + (long)m * G4 + n) = st;
    }
  }
}

// ---- kernel B: sequential LSTM, fp8 MFMA, weights pinned in AGPRs, LDS-buffered houts -----
// 16 blocks x 1024 threads (16 waves). Block bb owns batches 4bb..4bb+3.
// Wave w owns gate rows 16*(w+16*tau)+col, tau = i,f,g,o. Elementwise: (cb=col&3, r=col>>2)
// gives each lane a unique (batch, unit). One barrier/step; houts flushed every 8 steps.
#define WSCALE 64.f
#define HSCALE 16.f
#define DESCALE (1.f / (WSCALE * HSCALE))

__global__ __launch_bounds__(1024, 4) void kernelB(const _Float16* __restrict__ g_in,
                                                   const unsigned char* __restrict__ W8,
                                                   _Float16* __restrict__ houts) {
  int bb = blockIdx.x;
  int tid = threadIdx.x;
  int lane = tid & 63, w = tid >> 6;
  int col = lane & 15, quad = lane >> 4;
  int cb = col & 3;
  int r = col >> 2;

  __shared__ unsigned char h8[2][4 * 272];        // [buf][batch][k-permuted 256 + pad]
  __shared__ __align__(16) _Float16 hbuf[2][8][1024];  // [group][step][batch*256+unit], 32 KB

  for (int i = tid; i < 2 * 4 * 272; i += 1024) ((unsigned char*)h8)[i] = 0;

  // persistent A-fragments in AGPRs: wf[tau*8+c] = W8[16*(w+16*tau)+col][32c + quad*8 .. +7]
  unsigned long long wf[32];
#pragma unroll
  for (int tc = 0; tc < 32; tc++) {
    int tau = tc >> 3, c = tc & 7;
    wf[tc] = *(const unsigned long long*)(W8 + (unsigned)(16 * (w + 16 * tau) + col) * 256 + quad * 8 + 32 * c);
  }
#pragma unroll
  for (int tc = 0; tc < 32; tc++) asm volatile("" : "+a"(wf[tc]));  // pin in AGPRs

  int myk = 16 * w + 4 * quad + r;            // this lane's hidden unit
  int batch = 4 * bb + cb;                    // this lane's batch
  int myslot = cb * 272 + ((myk >> 3) & 3) * 64 + 16 * (myk >> 6) + 8 * ((myk >> 5) & 1) + (myk & 7);
  const unsigned char* bp0 = &h8[0][cb * 272 + quad * 64];
  const unsigned char* bp1 = &h8[1][cb * 272 + quad * 64];
  const _Float16* gbase = g_in + (long)batch * G4 + myk;

  float cst = 0.f;

  // preload g for t=0
  float gi_ = (float)gbase[0];
  float gf_ = (float)gbase[256];
  float gg_ = (float)gbase[512];
  float go_ = (float)gbase[768];
  const _Float16* gp = gbase + (long)B_ * G4;   // running prefetch pointer (t=1)

  __syncthreads();

  for (int t = 0; t < T_; t++) {
    // flush previous 8-step group of houts (issued right after barrier-exit -> full step to retire)
    if ((t & 7) == 0 && t > 0) {
      int g = ((t >> 3) & 1) ^ 1;
      int base_t = t - 8;
      int s = tid >> 7;                 // 128 uint4 per step-slot
      int w16 = (tid & 127) << 3;
      uint4 v = *(const uint4*)&hbuf[g][s][w16];
      *(uint4*)(houts + ((long)(base_t + s) * B_ + 4 * bb + (w16 >> 8)) * H_ + (w16 & 255)) = v;
    }
    // prefetch next step's g early (runs past end by 1 step into owned ws scratch; unused)
    float ngi = (float)gp[0];
    float ngf = (float)gp[256];
    float ngg = (float)gp[512];
    float ngo = (float)gp[768];
    gp += (long)B_ * G4;

    const unsigned char* bptr = (t & 1) ? bp1 : bp0;
    f4 acc0 = {0.f, 0.f, 0.f, 0.f}, acc1 = acc0, acc2 = acc0, acc3 = acc0;
#pragma unroll
    for (int i = 0; i < 4; i++) {
      ulonglong2 bv = *(const ulonglong2*)(bptr + i * 16);
      long long b0 = (long long)bv.x;
      long long b1 = (long long)bv.y;
      acc0 = __builtin_amdgcn_mfma_f32_16x16x32_fp8_fp8((long long)wf[0 * 8 + 2 * i], b0, acc0, 0, 0, 0);
      acc1 = __builtin_amdgcn_mfma_f32_16x16x32_fp8_fp8((long long)wf[1 * 8 + 2 * i], b0, acc1, 0, 0, 0);
      acc2 = __builtin_amdgcn_mfma_f32_16x16x32_fp8_fp8((long long)wf[2 * 8 + 2 * i], b0, acc2, 0, 0, 0);
      acc3 = __builtin_amdgcn_mfma_f32_16x16x32_fp8_fp8((long long)wf[3 * 8 + 2 * i], b0, acc3, 0, 0, 0);
      acc0 = __builtin_amdgcn_mfma_f32_16x16x32_fp8_fp8((long long)wf[0 * 8 + 2 * i + 1], b1, acc0, 0, 0, 0);
      acc1 = __builtin_amdgcn_mfma_f32_16x16x32_fp8_fp8((long long)wf[1 * 8 + 2 * i + 1], b1, acc1, 0, 0, 0);
      acc2 = __builtin_amdgcn_mfma_f32_16x16x32_fp8_fp8((long long)wf[2 * 8 + 2 * i + 1], b1, acc2, 0, 0, 0);
      acc3 = __builtin_amdgcn_mfma_f32_16x16x32_fp8_fp8((long long)wf[3 * 8 + 2 * i + 1], b1, acc3, 0, 0, 0);
    }

    // elementwise: this lane's single (batch, unit) = row r of its accs
    float gi = acc0[r] * DESCALE + gi_;
    float gf = acc1[r] * DESCALE + gf_;
    float gg = acc2[r] * DESCALE + gg_;
    float go = acc3[r] * DESCALE + go_;
    cst = sigf(gf) * cst + sigf(gi) * tanhfast(gg);
    float h = sigf(go) * tanhfast(cst);
    h8[1 - (t & 1)][myslot] = f32_e4m3(h * HSCALE);
    hbuf[(t >> 3) & 1][t & 7][cb * 256 + myk] = (_Float16)h;

    gi_ = ngi; gf_ = ngf; gg_ = ngg; go_ = ngo;
    __syncthreads();
  }
  // final flush: steps 504..511 live in group 1
  {
    int s = tid >> 7;
    int w16 = (tid & 127) << 3;
    uint4 v = *(const uint4*)&hbuf[1][s][w16];
    *(uint4*)(houts + ((long)(504 + s) * B_ + 4 * bb + (w16 >> 8)) * H_ + (w16 & 255)) = v;
  }
}

// ---- kernel C: emissions = houts(f16) @ W_lin^T + b_lin -----------------------------------
__global__ __launch_bounds__(256) void kernelC(const _Float16* __restrict__ houts,
                                               const float* __restrict__ W_lin,
                                               const float* __restrict__ b_lin,
                                               float* __restrict__ em) {
  __shared__ float hs[32][260];
  __shared__ float wl[20][260];
  __shared__ float bl[20];
  int bm = blockIdx.x;
  int tid = threadIdx.x;
  for (int i = tid; i < 32 * 64; i += 256) {
    int r = i >> 6, c = i & 63;
    uint2 v = *(const uint2*)(houts + ((long)(bm * 32 + r)) * H_ + c * 4);
    h2_t h0 = u2h(v.x), h1 = u2h(v.y);
    *(float4*)&hs[r][c * 4] = make_float4((float)h0.x, (float)h0.y, (float)h1.x, (float)h1.y);
  }
  for (int i = tid; i < 20 * 64; i += 256) {
    int k = i >> 6, c = i & 63;
    *(float4*)&wl[k][c * 4] = *(const float4*)(W_lin + k * H_ + c * 4);
  }
  if (tid < 20) bl[tid] = b_lin[tid];
  __syncthreads();
  for (int o = tid; o < 32 * 20; o += 256) {
    int r = o / 20, k = o % 20;
    float s = 0.f;
#pragma unroll 4
    for (int i = 0; i < H_; i++) s += hs[r][i] * wl[k][i];
    em[(long)bm * 32 * K_ + o] = s + bl[k];
  }
}

// ---- kernel D: CRF forward DP + gold score + NLL reduction --------------------------------
__global__ __launch_bounds__(64) void kernelD(const float* __restrict__ em,
                                              const int* __restrict__ labels,
                                              const float* __restrict__ start_t,
                                              const float* __restrict__ end_t,
                                              const float* __restrict__ trans,
                                              float* __restrict__ out) {
  int b = blockIdx.x;
  int k = threadIdx.x;
  __shared__ float tr[400];
  __shared__ float alpha[2][20];
  for (int i = k; i < 400; i += 64) tr[i] = trans[i];
  float score = 0.f;
  int prevtag = 0;
  if (k == 0) {
    int t0 = labels[b];
    score = start_t[t0] + em[b * K_ + t0];
    prevtag = t0;
  }
  if (k < K_) alpha[0][k] = start_t[k] + em[b * K_ + k];
  __syncthreads();
  int p = 0;
  for (int t = 1; t < T_; t++) {
    const float* emrow = em + ((long)t * B_ + b) * K_;
    if (k < K_) {
      float v[20];
      float m = -1e30f;
#pragma unroll
      for (int j = 0; j < 20; j++) {
        v[j] = alpha[p][j] + tr[j * 20 + k];
        m = fmaxf(m, v[j]);
      }
      float s = 0.f;
#pragma unroll
      for (int j = 0; j < 20; j++) s += __expf(v[j] - m);
      alpha[1 - p][k] = emrow[k] + m + __logf(s);
    }
    if (k == 0) {
      int tg = labels[t * B_ + b];
      score += tr[prevtag * 20 + tg] + emrow[tg];
      prevtag = tg;
    }
    p ^= 1;
    __syncthreads();
  }
  if (k == 0) {
    score += end_t[prevtag];
    float m = -1e30f;
    for (int j = 0; j < 20; j++) m = fmaxf(m, alpha[p][j] + end_t[j]);
    float s = 0.f;
    for (int j = 0; j < 20; j++) s += __expf(alpha[p][j] + end_t[j] - m);
    float logZ = m + __logf(s);
    atomicAdd(out, -(score - logZ));
  }
}

extern "C" void kernel_launch(void* const* d_in, const int* in_sizes, int n_in,
                              void* d_out, int out_size, void* d_ws, size_t ws_size,
                              hipStream_t stream) {
  const int*   inp     = (const int*)d_in[0];
  const int*   labels  = (const int*)d_in[1];
  const float* emb     = (const float*)d_in[2];
  const float* w_ih    = (const float*)d_in[3];
  const float* w_hh    = (const float*)d_in[4];
  const float* b_ih    = (const float*)d_in[5];
  const float* b_hh    = (const float*)d_in[6];
  const float* W_lin   = (const float*)d_in[7];
  const float* b_lin   = (const float*)d_in[8];
  const float* start_t = (const float*)d_in[9];
  const float* end_t   = (const float*)d_in[10];
  const float* trans   = (const float*)d_in[11];
  float* out = (float*)d_out;
  char* ws = (char*)d_ws;
  (void)ws_size;

  // ws layout (bytes), total ~91.6 MB:
  _Float16*       g_in   = (_Float16*)(ws);                       // 67,108,864 (T*B*1024 f16)
  unsigned short* Xh     = (unsigned short*)(ws + 67108864);      // 20,971,520 (32768x320 bf16)
  _Float16*       houts  = (_Float16*)(ws + 67108864);            // 16,777,216 — ALIASES Xh (Xh dead after kernelA)
  float*          em     = (float*)(ws + 88080384);               //  2,621,440 (T*B*K f32)
  unsigned short* wA     = (unsigned short*)(ws + 90701824);      //    655,360 (10x4x1024x8 bf16)
  unsigned char*  W8     = (unsigned char*)(ws + 91357184);       //    262,144 (1024x256 fp8)
  float*          b_comb = (float*)(ws + 91619328);               //      4,096

  prep_kernel<<<2048, 256, 0, stream>>>(inp, emb, w_ih, w_hh, b_ih, b_hh, Xh, wA, W8, b_comb, out);
  kernelA<<<4096, 256, 0, stream>>>(Xh, wA, b_comb, g_in);
  kernelB<<<16, 1024, 0, stream>>>(g_in, W8, houts);
  kernelC<<<1024, 256, 0, stream>>>(houts, W_lin, b_lin, em);
  kernelD<<<64, 64, 0, stream>>>(em, labels, start_t, end_t, trans, out);
}

// Round 7
// 1039.985 us; speedup vs baseline: 1.7423x; 1.3912x over previous
//
#include <hip/hip_runtime.h>
#include <math.h>

#define T_ 512
#define B_ 64
#define V_ 50000
#define E_ 300
#define H_ 256
#define K_ 20
#define G4 1024  /* 4*H */

typedef float f4 __attribute__((ext_vector_type(4)));
typedef int v4i __attribute__((ext_vector_type(4)));
typedef short bf16x8 __attribute__((ext_vector_type(8)));
typedef _Float16 h2_t __attribute__((ext_vector_type(2)));
union U32H2 { unsigned u; h2_t h; };
__device__ __forceinline__ h2_t u2h(unsigned u) { U32H2 x; x.u = u; return x.h; }
__device__ __forceinline__ unsigned h2u(h2_t h) { U32H2 x; x.h = h; return x.u; }

__device__ __forceinline__ float sigf(float x) { return 1.f / (1.f + __expf(-x)); }
__device__ __forceinline__ float tanhfast(float x) { return 1.f - 2.f / (__expf(2.f * x) + 1.f); }

__device__ __forceinline__ unsigned short f32_bf16(float x) {
  union { float f; unsigned u; } v; v.f = x;
  v.u += 0x7FFFu + ((v.u >> 16) & 1u);   // RTNE
  return (unsigned short)(v.u >> 16);
}

#define WSCALE_I 2032.f   /* |w| <= 1/16 -> +-127 */
#define HSCALE_I 127.f    /* |h| < 1    -> +-127 */
#define DESCALE_I (1.f / (WSCALE_I * HSCALE_I))

// ---- prep: gather X=bf16(emb[inp]) (K padded to 320), pack w_ih A-frags, quantize w_hh i8,
//      combine biases, zero out ------------------------------------------------------------
__global__ void prep_kernel(const int* __restrict__ inp,
                            const float* __restrict__ emb,
                            const float* __restrict__ w_ih, const float* __restrict__ w_hh,
                            const float* __restrict__ b_ih, const float* __restrict__ b_hh,
                            unsigned short* __restrict__ Xh, unsigned short* __restrict__ wA,
                            signed char* __restrict__ W8,
                            float* __restrict__ b_comb, float* __restrict__ out) {
  int tid = blockIdx.x * blockDim.x + threadIdx.x;
  int nth = gridDim.x * blockDim.x;
  for (int i = tid; i < 32768 * 80; i += nth) {
    int row = i / 80, c4 = i % 80, k = c4 * 4;
    ushort4 st;
    if (c4 < 75) {
      int tok = inp[row];
      float4 v = *(const float4*)(emb + (long)tok * E_ + k);
      st.x = f32_bf16(v.x); st.y = f32_bf16(v.y); st.z = f32_bf16(v.z); st.w = f32_bf16(v.w);
    } else {
      st.x = st.y = st.z = st.w = 0;
    }
    *(ushort4*)(Xh + (long)row * 320 + k) = st;
  }
  for (int i = tid; i < 10 * 4 * 1024 * 8; i += nth) {
    int j = i & 7, n = (i >> 3) & 1023, q = (i >> 13) & 3, c = i >> 15;
    int k = c * 32 + q * 8 + j;
    wA[i] = (k < E_) ? f32_bf16(w_ih[n * E_ + k]) : 0;
  }
  // W8[row][k] = i8(round(w_hh[row][k] * 2032)), clamped
  for (int i = tid; i < G4 * H_; i += nth) {
    float v = fminf(fmaxf(w_hh[i] * WSCALE_I, -127.f), 127.f);
    W8[i] = (signed char)__float2int_rn(v);
  }
  for (int i = tid; i < G4; i += nth) b_comb[i] = b_ih[i] + b_hh[i];
  if (tid == 0) out[0] = 0.f;
}

// ---- kernel A: g_in (f16) = X @ w_ih^T + b, via bf16 MFMA ---------------------------------
__global__ __launch_bounds__(256) void kernelA(const unsigned short* __restrict__ Xh,
                                               const unsigned short* __restrict__ wA,
                                               const float* __restrict__ b_comb,
                                               _Float16* __restrict__ g_in) {
  __shared__ __align__(16) unsigned short xs[32 * 328];
  int bm = blockIdx.x >> 2, bn = blockIdx.x & 3;
  int tid = threadIdx.x;
  for (int i = tid; i < 32 * 40; i += 256) {
    int r = i / 40, c = i % 40;
    *(uint4*)&xs[r * 328 + c * 8] = *(const uint4*)(Xh + (long)(bm * 32 + r) * 320 + c * 8);
  }
  __syncthreads();
  int lane = tid & 63, w = tid >> 6, col = lane & 15, quad = lane >> 4;
  int nbase = bn * 256 + w * 64;
  f4 acc[2][4];
#pragma unroll
  for (int mt = 0; mt < 2; mt++)
#pragma unroll
    for (int nt = 0; nt < 4; nt++) acc[mt][nt] = (f4){0.f, 0.f, 0.f, 0.f};
#pragma unroll 2
  for (int c = 0; c < 10; c++) {
    bf16x8 a[4], b[2];
#pragma unroll
    for (int nt = 0; nt < 4; nt++)
      a[nt] = *(const bf16x8*)(wA + (((long)c * 4 + quad) * 1024 + nbase + nt * 16 + col) * 8);
#pragma unroll
    for (int mt = 0; mt < 2; mt++)
      b[mt] = *(const bf16x8*)&xs[(mt * 16 + col) * 328 + c * 32 + quad * 8];
#pragma unroll
    for (int mt = 0; mt < 2; mt++)
#pragma unroll
      for (int nt = 0; nt < 4; nt++)
        acc[mt][nt] = __builtin_amdgcn_mfma_f32_16x16x32_bf16(a[nt], b[mt], acc[mt][nt], 0, 0, 0);
  }
#pragma unroll
  for (int mt = 0; mt < 2; mt++) {
    int m = bm * 32 + mt * 16 + col;
#pragma unroll
    for (int nt = 0; nt < 4; nt++) {
      int n = nbase + nt * 16 + quad * 4;
      f4 o = acc[mt][nt] + *(const f4*)(b_comb + n);
      h2_t p0, p1;
      p0.x = (_Float16)o.x; p0.y = (_Float16)o.y;
      p1.x = (_Float16)o.z; p1.y = (_Float16)o.w;
      uint2 st; st.x = h2u(p0); st.y = h2u(p1);
      *(uint2*)(g_in + (long)m * G4 + n) = st;
    }
  }
}

// ---- kernel B: sequential LSTM, i8 K=64 MFMA, weights pinned in AGPRs ---------------------
// 16 blocks x 1024 threads (16 waves). Block bb owns batches 4bb..4bb+3 (broadcast x4 in cols).
// Wave w owns gate rows 16*(w+16*tau)+col, tau = i,f,g,o -> 4 chunks of K=64 each = 16 MFMA/step.
// Lane's elementwise: (cb=col&3, r=col>>2) -> unique (batch, unit). One barrier per step.
// h8 layout per batch (stride 288): unit u at offset 64*((u>>4)&3) + 16*(u>>6) + (u&15);
// read for chunk c, quad q = 16B at 64q + 16c  (k = 64c + 16q + j).
__global__ __launch_bounds__(1024, 4) void kernelB(const _Float16* __restrict__ g_in,
                                                   const signed char* __restrict__ W8,
                                                   _Float16* __restrict__ houts) {
  int bb = blockIdx.x;
  int tid = threadIdx.x;
  int lane = tid & 63, w = tid >> 6;
  int col = lane & 15, quad = lane >> 4;
  int cb = col & 3;
  int r = col >> 2;

  __shared__ __align__(16) signed char h8[2][4 * 288];       // [buf][batch][k layout 256 + pad]
  __shared__ __align__(16) _Float16 hlin[2][1024];           // [buf][batch*256+unit], 4 KB

  for (int i = tid; i < 2 * 4 * 288; i += 1024) ((signed char*)h8)[i] = 0;

  // persistent A-fragments in AGPRs: wf[tau*4+c] = W8[16*(w+16*tau)+col][64c + 16*quad .. +15]
  v4i wf[16];
#pragma unroll
  for (int tc = 0; tc < 16; tc++) {
    int tau = tc >> 2, c = tc & 3;
    const signed char* rp = W8 + (unsigned)(16 * (w + 16 * tau) + col) * 256 + 64 * c + 16 * quad;
    uint4 q0 = *(const uint4*)rp;
    wf[tc] = (v4i){(int)q0.x, (int)q0.y, (int)q0.z, (int)q0.w};
  }
#pragma unroll
  for (int tc = 0; tc < 16; tc++) asm volatile("" : "+a"(wf[tc]));  // pin in AGPRs

  int myk = 16 * w + 4 * quad + r;            // this lane's hidden unit
  int batch = 4 * bb + cb;                    // this lane's batch
  int myslot = cb * 288 + 64 * ((myk >> 4) & 3) + 16 * (myk >> 6) + (myk & 15);
  const signed char* bp0 = &h8[0][cb * 288 + 64 * quad];
  const signed char* bp1 = &h8[1][cb * 288 + 64 * quad];
  const _Float16* gbase = g_in + (long)batch * G4 + myk;

  float cst = 0.f;
  float gi_ = (float)gbase[0];
  float gf_ = (float)gbase[256];
  float gg_ = (float)gbase[512];
  float go_ = (float)gbase[768];
  const _Float16* gp = gbase + (long)B_ * G4;   // running prefetch pointer (t=1)

  __syncthreads();

  for (int t = 0; t < T_; t++) {
    // flush previous step's houts from LDS (coalesced, overlaps this step's MFMAs)
    if (t > 0 && tid < 128) {
      int buf = (t - 1) & 1;
      uint4 v = *(const uint4*)&hlin[buf][tid * 8];
      *(uint4*)(houts + ((long)(t - 1) * B_ + 4 * bb + (tid >> 5)) * H_ + ((tid * 8) & 255)) = v;
    }
    // prefetch next step's g early
    float ngi = (float)gp[0];
    float ngf = (float)gp[256];
    float ngg = (float)gp[512];
    float ngo = (float)gp[768];
    gp += (long)B_ * G4;

    const signed char* bptr = (t & 1) ? bp1 : bp0;
    v4i b0 = *(const v4i*)(bptr);
    v4i b1 = *(const v4i*)(bptr + 16);
    v4i b2 = *(const v4i*)(bptr + 32);
    v4i b3 = *(const v4i*)(bptr + 48);
    v4i a0 = {0, 0, 0, 0}, a1 = a0, a2 = a0, a3 = a0;
    a0 = __builtin_amdgcn_mfma_i32_16x16x64_i8(wf[0],  b0, a0, 0, 0, 0);
    a1 = __builtin_amdgcn_mfma_i32_16x16x64_i8(wf[4],  b0, a1, 0, 0, 0);
    a2 = __builtin_amdgcn_mfma_i32_16x16x64_i8(wf[8],  b0, a2, 0, 0, 0);
    a3 = __builtin_amdgcn_mfma_i32_16x16x64_i8(wf[12], b0, a3, 0, 0, 0);
    a0 = __builtin_amdgcn_mfma_i32_16x16x64_i8(wf[1],  b1, a0, 0, 0, 0);
    a1 = __builtin_amdgcn_mfma_i32_16x16x64_i8(wf[5],  b1, a1, 0, 0, 0);
    a2 = __builtin_amdgcn_mfma_i32_16x16x64_i8(wf[9],  b1, a2, 0, 0, 0);
    a3 = __builtin_amdgcn_mfma_i32_16x16x64_i8(wf[13], b1, a3, 0, 0, 0);
    a0 = __builtin_amdgcn_mfma_i32_16x16x64_i8(wf[2],  b2, a0, 0, 0, 0);
    a1 = __builtin_amdgcn_mfma_i32_16x16x64_i8(wf[6],  b2, a1, 0, 0, 0);
    a2 = __builtin_amdgcn_mfma_i32_16x16x64_i8(wf[10], b2, a2, 0, 0, 0);
    a3 = __builtin_amdgcn_mfma_i32_16x16x64_i8(wf[14], b2, a3, 0, 0, 0);
    a0 = __builtin_amdgcn_mfma_i32_16x16x64_i8(wf[3],  b3, a0, 0, 0, 0);
    a1 = __builtin_amdgcn_mfma_i32_16x16x64_i8(wf[7],  b3, a1, 0, 0, 0);
    a2 = __builtin_amdgcn_mfma_i32_16x16x64_i8(wf[11], b3, a2, 0, 0, 0);
    a3 = __builtin_amdgcn_mfma_i32_16x16x64_i8(wf[15], b3, a3, 0, 0, 0);

    // elementwise: this lane's single (batch, unit) = row r of its accs
    float gi = (float)a0[r] * DESCALE_I + gi_;
    float gf = (float)a1[r] * DESCALE_I + gf_;
    float gg = (float)a2[r] * DESCALE_I + gg_;
    float go = (float)a3[r] * DESCALE_I + go_;
    cst = sigf(gf) * cst + sigf(gi) * tanhfast(gg);
    float h = sigf(go) * tanhfast(cst);
    h8[1 - (t & 1)][myslot] = (signed char)__float2int_rn(h * HSCALE_I);
    hlin[t & 1][cb * 256 + myk] = (_Float16)h;

    gi_ = ngi; gf_ = ngf; gg_ = ngg; go_ = ngo;
    __syncthreads();
  }
  // final flush: step 511 lives in buf 1
  if (tid < 128) {
    uint4 v = *(const uint4*)&hlin[1][tid * 8];
    *(uint4*)(houts + ((long)511 * B_ + 4 * bb + (tid >> 5)) * H_ + ((tid * 8) & 255)) = v;
  }
}

// ---- kernel C: emissions = houts(f16) @ W_lin^T + b_lin -----------------------------------
__global__ __launch_bounds__(256) void kernelC(const _Float16* __restrict__ houts,
                                               const float* __restrict__ W_lin,
                                               const float* __restrict__ b_lin,
                                               float* __restrict__ em) {
  __shared__ float hs[32][260];
  __shared__ float wl[20][260];
  __shared__ float bl[20];
  int bm = blockIdx.x;
  int tid = threadIdx.x;
  for (int i = tid; i < 32 * 64; i += 256) {
    int r = i >> 6, c = i & 63;
    uint2 v = *(const uint2*)(houts + ((long)(bm * 32 + r)) * H_ + c * 4);
    h2_t h0 = u2h(v.x), h1 = u2h(v.y);
    *(float4*)&hs[r][c * 4] = make_float4((float)h0.x, (float)h0.y, (float)h1.x, (float)h1.y);
  }
  for (int i = tid; i < 20 * 64; i += 256) {
    int k = i >> 6, c = i & 63;
    *(float4*)&wl[k][c * 4] = *(const float4*)(W_lin + k * H_ + c * 4);
  }
  if (tid < 20) bl[tid] = b_lin[tid];
  __syncthreads();
  for (int o = tid; o < 32 * 20; o += 256) {
    int r = o / 20, k = o % 20;
    float s = 0.f;
#pragma unroll 4
    for (int i = 0; i < H_; i++) s += hs[r][i] * wl[k][i];
    em[(long)bm * 32 * K_ + o] = s + bl[k];
  }
}

// ---- kernel D: CRF. wave0: forward DP in exp-domain (E=exp(trans) matvec); wave1: gold score.
__global__ __launch_bounds__(128) void kernelD(const float* __restrict__ em,
                                               const int* __restrict__ labels,
                                               const float* __restrict__ start_t,
                                               const float* __restrict__ end_t,
                                               const float* __restrict__ trans,
                                               float* __restrict__ out) {
  int b = blockIdx.x;
  int tid = threadIdx.x;
  int lane = tid & 63;
  int wv = tid >> 6;
  if (wv == 0) {
    int k = lane & 31;
    bool vk = (lane < K_) && (lane < 32);
    int kk = vk ? k : 0;
    float Ej[20];
#pragma unroll
    for (int j = 0; j < 20; j++) Ej[j] = vk ? __expf(trans[j * 20 + k]) : 0.f;
    float eend = vk ? __expf(end_t[kk]) : 0.f;
    float alpha = vk ? (start_t[kk] + em[b * K_ + kk]) : -1e30f;
    float emk = em[(64 + b) * K_ + kk];   // t = 1
    for (int t = 1; t < T_; t++) {
      float em_next = (t < T_ - 1) ? em[((long)(t + 1) * B_ + b) * K_ + kk] : 0.f;
      float m = alpha;
#pragma unroll
      for (int off = 16; off >= 1; off >>= 1) m = fmaxf(m, __shfl_xor(m, off, 32));
      float e = __expf(alpha - m);
      float S = 0.f;
#pragma unroll
      for (int j = 0; j < 20; j++) S = fmaf(__shfl(e, j, 32), Ej[j], S);
      alpha = vk ? (emk + m + __logf(S)) : -1e30f;
      emk = em_next;
    }
    // logZ
    float m = alpha;
#pragma unroll
    for (int off = 16; off >= 1; off >>= 1) m = fmaxf(m, __shfl_xor(m, off, 32));
    float e = __expf(alpha - m) * eend;
#pragma unroll
    for (int off = 16; off >= 1; off >>= 1) e += __shfl_xor(e, off, 32);
    if (lane == 0) atomicAdd(out, m + __logf(e));
  } else {
    // gold-path score: order-free sum, lane l covers t = 8l..8l+7
    int t0 = 8 * lane;
    int tags[9];
#pragma unroll
    for (int i = 0; i < 9; i++) {
      int t = t0 - 1 + i;
      tags[i] = (t >= 0) ? labels[t * B_ + b] : 0;
    }
    float sc = 0.f;
#pragma unroll
    for (int i = 1; i < 9; i++) {
      int t = t0 - 1 + i;
      float v = em[((long)t * B_ + b) * K_ + tags[i]];
      v += (t > 0) ? trans[tags[i - 1] * 20 + tags[i]] : start_t[tags[i]];
      sc += v;
    }
#pragma unroll
    for (int off = 32; off >= 1; off >>= 1) sc += __shfl_xor(sc, off, 64);
    if (lane == 0) {
      sc += end_t[labels[511 * B_ + b]];
      atomicAdd(out, -sc);
    }
  }
}

extern "C" void kernel_launch(void* const* d_in, const int* in_sizes, int n_in,
                              void* d_out, int out_size, void* d_ws, size_t ws_size,
                              hipStream_t stream) {
  const int*   inp     = (const int*)d_in[0];
  const int*   labels  = (const int*)d_in[1];
  const float* emb     = (const float*)d_in[2];
  const float* w_ih    = (const float*)d_in[3];
  const float* w_hh    = (const float*)d_in[4];
  const float* b_ih    = (const float*)d_in[5];
  const float* b_hh    = (const float*)d_in[6];
  const float* W_lin   = (const float*)d_in[7];
  const float* b_lin   = (const float*)d_in[8];
  const float* start_t = (const float*)d_in[9];
  const float* end_t   = (const float*)d_in[10];
  const float* trans   = (const float*)d_in[11];
  float* out = (float*)d_out;
  char* ws = (char*)d_ws;
  (void)ws_size;

  // ws layout (bytes), total ~91.6 MB:
  _Float16*       g_in   = (_Float16*)(ws);                       // 67,108,864 (T*B*1024 f16)
  unsigned short* Xh     = (unsigned short*)(ws + 67108864);      // 20,971,520 (32768x320 bf16)
  _Float16*       houts  = (_Float16*)(ws + 67108864);            // 16,777,216 — ALIASES Xh (Xh dead after kernelA)
  float*          em     = (float*)(ws + 88080384);               //  2,621,440 (T*B*K f32)
  unsigned short* wA     = (unsigned short*)(ws + 90701824);      //    655,360 (10x4x1024x8 bf16)
  signed char*    W8     = (signed char*)(ws + 91357184);         //    262,144 (1024x256 i8)
  float*          b_comb = (float*)(ws + 91619328);               //      4,096

  prep_kernel<<<2048, 256, 0, stream>>>(inp, emb, w_ih, w_hh, b_ih, b_hh, Xh, wA, W8, b_comb, out);
  kernelA<<<4096, 256, 0, stream>>>(Xh, wA, b_comb, g_in);
  kernelB<<<16, 1024, 0, stream>>>(g_in, W8, houts);
  kernelC<<<1024, 256, 0, stream>>>(houts, W_lin, b_lin, em);
  kernelD<<<64, 128, 0, stream>>>(em, labels, start_t, end_t, trans, out);
}

// Round 8
// 940.877 us; speedup vs baseline: 1.9258x; 1.1053x over previous
//
#include <hip/hip_runtime.h>
#include <math.h>

#define T_ 512
#define B_ 64
#define V_ 50000
#define E_ 300
#define H_ 256
#define K_ 20
#define G4 1024  /* 4*H */
#define LOG2E 1.44269504f

typedef float f4 __attribute__((ext_vector_type(4)));
typedef int v4i __attribute__((ext_vector_type(4)));
typedef short bf16x8 __attribute__((ext_vector_type(8)));
typedef _Float16 h2_t __attribute__((ext_vector_type(2)));
union U32H2 { unsigned u; h2_t h; };
__device__ __forceinline__ h2_t u2h(unsigned u) { U32H2 x; x.u = u; return x.h; }
__device__ __forceinline__ unsigned h2u(h2_t h) { U32H2 x; x.h = h; return x.u; }

__device__ __forceinline__ float rcpf(float x) { return __builtin_amdgcn_rcpf(x); }
__device__ __forceinline__ float exp2f_(float x) { return __builtin_amdgcn_exp2f(x); }

__device__ __forceinline__ unsigned short f32_bf16(float x) {
  union { float f; unsigned u; } v; v.f = x;
  v.u += 0x7FFFu + ((v.u >> 16) & 1u);   // RTNE
  return (unsigned short)(v.u >> 16);
}

#define WSCALE_I 2032.f   /* |w| <= 1/16 -> +-127 */
#define HSCALE_I 127.f    /* |h| < 1    -> +-127 */
#define DESCALE_I (1.f / (WSCALE_I * HSCALE_I))
#define DESCALE2 (DESCALE_I * LOG2E)

// ---- prep: gather X=bf16(emb[inp]) (K padded to 320), pack w_ih A-frags, quantize w_hh i8,
//      combine biases, zero out ------------------------------------------------------------
__global__ void prep_kernel(const int* __restrict__ inp,
                            const float* __restrict__ emb,
                            const float* __restrict__ w_ih, const float* __restrict__ w_hh,
                            const float* __restrict__ b_ih, const float* __restrict__ b_hh,
                            unsigned short* __restrict__ Xh, unsigned short* __restrict__ wA,
                            signed char* __restrict__ W8,
                            float* __restrict__ b_comb, float* __restrict__ out) {
  int tid = blockIdx.x * blockDim.x + threadIdx.x;
  int nth = gridDim.x * blockDim.x;
  for (int i = tid; i < 32768 * 80; i += nth) {
    int row = i / 80, c4 = i % 80, k = c4 * 4;
    ushort4 st;
    if (c4 < 75) {
      int tok = inp[row];
      float4 v = *(const float4*)(emb + (long)tok * E_ + k);
      st.x = f32_bf16(v.x); st.y = f32_bf16(v.y); st.z = f32_bf16(v.z); st.w = f32_bf16(v.w);
    } else {
      st.x = st.y = st.z = st.w = 0;
    }
    *(ushort4*)(Xh + (long)row * 320 + k) = st;
  }
  for (int i = tid; i < 10 * 4 * 1024 * 8; i += nth) {
    int j = i & 7, n = (i >> 3) & 1023, q = (i >> 13) & 3, c = i >> 15;
    int k = c * 32 + q * 8 + j;
    wA[i] = (k < E_) ? f32_bf16(w_ih[n * E_ + k]) : 0;
  }
  // W8[row][k] = i8(round(w_hh[row][k] * 2032)), clamped
  for (int i = tid; i < G4 * H_; i += nth) {
    float v = fminf(fmaxf(w_hh[i] * WSCALE_I, -127.f), 127.f);
    W8[i] = (signed char)__float2int_rn(v);
  }
  for (int i = tid; i < G4; i += nth) b_comb[i] = b_ih[i] + b_hh[i];
  if (tid == 0) out[0] = 0.f;
}

// ---- kernel A: g_in (f16) = (X @ w_ih^T + b) * log2(e), via bf16 MFMA ---------------------
// Pre-scaling by log2e lets kernelB's sigmoids/tanh use raw v_exp_f32 (exp2) without a mul.
__global__ __launch_bounds__(256) void kernelA(const unsigned short* __restrict__ Xh,
                                               const unsigned short* __restrict__ wA,
                                               const float* __restrict__ b_comb,
                                               _Float16* __restrict__ g_in) {
  __shared__ __align__(16) unsigned short xs[32 * 328];
  int bm = blockIdx.x >> 2, bn = blockIdx.x & 3;
  int tid = threadIdx.x;
  for (int i = tid; i < 32 * 40; i += 256) {
    int r = i / 40, c = i % 40;
    *(uint4*)&xs[r * 328 + c * 8] = *(const uint4*)(Xh + (long)(bm * 32 + r) * 320 + c * 8);
  }
  __syncthreads();
  int lane = tid & 63, w = tid >> 6, col = lane & 15, quad = lane >> 4;
  int nbase = bn * 256 + w * 64;
  f4 acc[2][4];
#pragma unroll
  for (int mt = 0; mt < 2; mt++)
#pragma unroll
    for (int nt = 0; nt < 4; nt++) acc[mt][nt] = (f4){0.f, 0.f, 0.f, 0.f};
#pragma unroll 2
  for (int c = 0; c < 10; c++) {
    bf16x8 a[4], b[2];
#pragma unroll
    for (int nt = 0; nt < 4; nt++)
      a[nt] = *(const bf16x8*)(wA + (((long)c * 4 + quad) * 1024 + nbase + nt * 16 + col) * 8);
#pragma unroll
    for (int mt = 0; mt < 2; mt++)
      b[mt] = *(const bf16x8*)&xs[(mt * 16 + col) * 328 + c * 32 + quad * 8];
#pragma unroll
    for (int mt = 0; mt < 2; mt++)
#pragma unroll
      for (int nt = 0; nt < 4; nt++)
        acc[mt][nt] = __builtin_amdgcn_mfma_f32_16x16x32_bf16(a[nt], b[mt], acc[mt][nt], 0, 0, 0);
  }
#pragma unroll
  for (int mt = 0; mt < 2; mt++) {
    int m = bm * 32 + mt * 16 + col;
#pragma unroll
    for (int nt = 0; nt < 4; nt++) {
      int n = nbase + nt * 16 + quad * 4;
      f4 o = (acc[mt][nt] + *(const f4*)(b_comb + n)) * LOG2E;
      h2_t p0, p1;
      p0.x = (_Float16)o.x; p0.y = (_Float16)o.y;
      p1.x = (_Float16)o.z; p1.y = (_Float16)o.w;
      uint2 st; st.x = h2u(p0); st.y = h2u(p1);
      *(uint2*)(g_in + (long)m * G4 + n) = st;
    }
  }
}

// ---- kernel B: sequential LSTM, i8 K=64 MFMA, weights pinned in AGPRs ---------------------
// 16 blocks x 1024 threads (16 waves). Block bb owns batches 4bb..4bb+3 (broadcast x4 in cols).
// Wave w owns gate rows 16*(w+16*tau)+col, tau = i,f,g,o -> 4 chunks of K=64 each = 16 MFMA/step.
// Lane's elementwise: (cb=col&3, r=col>>2) -> unique (batch, unit). One barrier per step.
// h8 k-major layout: byte for (batch cb, unit u) at 256*(u>>6) + 64*((u>>4)&3) + 16*cb + (u&15).
// Read (chunk c, quad q, batch cb) = 16B at 256c + 64q + 16cb -> banks 16q+4cb: exact 2-way (free).
__global__ __launch_bounds__(1024, 4) void kernelB(const _Float16* __restrict__ g_in,
                                                   const signed char* __restrict__ W8,
                                                   _Float16* __restrict__ houts) {
  int bb = blockIdx.x;
  int tid = threadIdx.x;
  int lane = tid & 63, w = tid >> 6;
  int col = lane & 15, quad = lane >> 4;
  int cb = col & 3;
  int r = col >> 2;

  __shared__ __align__(16) signed char h8[2][1024];          // [buf][k-major 4*256]
  __shared__ __align__(16) _Float16 hlin[2][1024];           // [buf][batch*256+unit], 4 KB

  for (int i = tid; i < 2 * 1024; i += 1024) ((signed char*)h8)[i] = 0;

  // persistent A-fragments in AGPRs: wf[tau*4+c] = W8[16*(w+16*tau)+col][64c + 16*quad .. +15]
  v4i wf[16];
#pragma unroll
  for (int tc = 0; tc < 16; tc++) {
    int tau = tc >> 2, c = tc & 3;
    const signed char* rp = W8 + (unsigned)(16 * (w + 16 * tau) + col) * 256 + 64 * c + 16 * quad;
    uint4 q0 = *(const uint4*)rp;
    wf[tc] = (v4i){(int)q0.x, (int)q0.y, (int)q0.z, (int)q0.w};
  }
#pragma unroll
  for (int tc = 0; tc < 16; tc++) asm volatile("" : "+a"(wf[tc]));  // pin in AGPRs

  int myk = 16 * w + 4 * quad + r;            // this lane's hidden unit
  int batch = 4 * bb + cb;                    // this lane's batch
  int myslot = 256 * (w >> 2) + 64 * (w & 3) + 16 * cb + 4 * quad + r;
  const signed char* bp0 = &h8[0][64 * quad + 16 * cb];
  const signed char* bp1 = &h8[1][64 * quad + 16 * cb];
  const _Float16* gbase = g_in + (long)batch * G4 + myk;

  float cst = 0.f;
  float gi_ = (float)gbase[0];
  float gf_ = (float)gbase[256];
  float gg_ = (float)gbase[512];
  float go_ = (float)gbase[768];
  const _Float16* gp = gbase + (long)B_ * G4;   // running prefetch pointer (t=1)

  __syncthreads();

  for (int t = 0; t < T_; t++) {
    // flush previous step's houts from LDS (coalesced, overlaps this step's MFMAs)
    if (t > 0 && tid < 128) {
      int buf = (t - 1) & 1;
      uint4 v = *(const uint4*)&hlin[buf][tid * 8];
      *(uint4*)(houts + ((long)(t - 1) * B_ + 4 * bb + (tid >> 5)) * H_ + ((tid * 8) & 255)) = v;
    }
    // prefetch next step's g early
    float ngi = (float)gp[0];
    float ngf = (float)gp[256];
    float ngg = (float)gp[512];
    float ngo = (float)gp[768];
    gp += (long)B_ * G4;

    const signed char* bptr = (t & 1) ? bp1 : bp0;
    v4i b0 = *(const v4i*)(bptr);
    v4i b1 = *(const v4i*)(bptr + 256);
    v4i b2 = *(const v4i*)(bptr + 512);
    v4i b3 = *(const v4i*)(bptr + 768);
    v4i a0 = {0, 0, 0, 0}, a1 = a0, a2 = a0, a3 = a0;
    a0 = __builtin_amdgcn_mfma_i32_16x16x64_i8(wf[0],  b0, a0, 0, 0, 0);
    a1 = __builtin_amdgcn_mfma_i32_16x16x64_i8(wf[4],  b0, a1, 0, 0, 0);
    a2 = __builtin_amdgcn_mfma_i32_16x16x64_i8(wf[8],  b0, a2, 0, 0, 0);
    a3 = __builtin_amdgcn_mfma_i32_16x16x64_i8(wf[12], b0, a3, 0, 0, 0);
    a0 = __builtin_amdgcn_mfma_i32_16x16x64_i8(wf[1],  b1, a0, 0, 0, 0);
    a1 = __builtin_amdgcn_mfma_i32_16x16x64_i8(wf[5],  b1, a1, 0, 0, 0);
    a2 = __builtin_amdgcn_mfma_i32_16x16x64_i8(wf[9],  b1, a2, 0, 0, 0);
    a3 = __builtin_amdgcn_mfma_i32_16x16x64_i8(wf[13], b1, a3, 0, 0, 0);
    a0 = __builtin_amdgcn_mfma_i32_16x16x64_i8(wf[2],  b2, a0, 0, 0, 0);
    a1 = __builtin_amdgcn_mfma_i32_16x16x64_i8(wf[6],  b2, a1, 0, 0, 0);
    a2 = __builtin_amdgcn_mfma_i32_16x16x64_i8(wf[10], b2, a2, 0, 0, 0);
    a3 = __builtin_amdgcn_mfma_i32_16x16x64_i8(wf[14], b2, a3, 0, 0, 0);
    a0 = __builtin_amdgcn_mfma_i32_16x16x64_i8(wf[3],  b3, a0, 0, 0, 0);
    a1 = __builtin_amdgcn_mfma_i32_16x16x64_i8(wf[7],  b3, a1, 0, 0, 0);
    a2 = __builtin_amdgcn_mfma_i32_16x16x64_i8(wf[11], b3, a2, 0, 0, 0);
    a3 = __builtin_amdgcn_mfma_i32_16x16x64_i8(wf[15], b3, a3, 0, 0, 0);

    // elementwise in log2e-prescaled domain: sigma(x) = rcp(1+exp2(-x))
    float gi = (float)a0[r] * DESCALE2 + gi_;
    float gf = (float)a1[r] * DESCALE2 + gf_;
    float gg = (float)a2[r] * DESCALE2 + gg_;
    float go = (float)a3[r] * DESCALE2 + go_;
    float si = rcpf(1.f + exp2f_(-gi));
    float sf = rcpf(1.f + exp2f_(-gf));
    float so = rcpf(1.f + exp2f_(-go));
    float tg = 1.f - 2.f * rcpf(1.f + exp2f_(gg + gg));          // tanh(gg_real)
    cst = sf * cst + si * tg;
    float tc_ = 1.f - 2.f * rcpf(1.f + exp2f_(2.88539008f * cst)); // tanh(cst)
    float h = so * tc_;
    h8[1 - (t & 1)][myslot] = (signed char)__float2int_rn(h * HSCALE_I);
    hlin[t & 1][cb * 256 + myk] = (_Float16)h;

    gi_ = ngi; gf_ = ngf; gg_ = ngg; go_ = ngo;
    __syncthreads();
  }
  // final flush: step 511 lives in buf 1
  if (tid < 128) {
    uint4 v = *(const uint4*)&hlin[1][tid * 8];
    *(uint4*)(houts + ((long)511 * B_ + 4 * bb + (tid >> 5)) * H_ + ((tid * 8) & 255)) = v;
  }
}

// ---- kernel C: emissions = houts(f16) @ W_lin^T + b_lin -----------------------------------
__global__ __launch_bounds__(256) void kernelC(const _Float16* __restrict__ houts,
                                               const float* __restrict__ W_lin,
                                               const float* __restrict__ b_lin,
                                               float* __restrict__ em) {
  __shared__ float hs[32][260];
  __shared__ float wl[20][260];
  __shared__ float bl[20];
  int bm = blockIdx.x;
  int tid = threadIdx.x;
  for (int i = tid; i < 32 * 64; i += 256) {
    int r = i >> 6, c = i & 63;
    uint2 v = *(const uint2*)(houts + ((long)(bm * 32 + r)) * H_ + c * 4);
    h2_t h0 = u2h(v.x), h1 = u2h(v.y);
    *(float4*)&hs[r][c * 4] = make_float4((float)h0.x, (float)h0.y, (float)h1.x, (float)h1.y);
  }
  for (int i = tid; i < 20 * 64; i += 256) {
    int k = i >> 6, c = i & 63;
    *(float4*)&wl[k][c * 4] = *(const float4*)(W_lin + k * H_ + c * 4);
  }
  if (tid < 20) bl[tid] = b_lin[tid];
  __syncthreads();
  for (int o = tid; o < 32 * 20; o += 256) {
    int r = o / 20, k = o % 20;
    float s = 0.f;
#pragma unroll 4
    for (int i = 0; i < H_; i++) s += hs[r][i] * wl[k][i];
    em[(long)bm * 32 * K_ + o] = s + bl[k];
  }
}

// ---- kernel D: CRF. wave0: forward DP in exp-domain (E=exp(trans) matvec); wave1: gold score.
__global__ __launch_bounds__(128) void kernelD(const float* __restrict__ em,
                                               const int* __restrict__ labels,
                                               const float* __restrict__ start_t,
                                               const float* __restrict__ end_t,
                                               const float* __restrict__ trans,
                                               float* __restrict__ out) {
  int b = blockIdx.x;
  int tid = threadIdx.x;
  int lane = tid & 63;
  int wv = tid >> 6;
  if (wv == 0) {
    int k = lane & 31;
    bool vk = (lane < K_) && (lane < 32);
    int kk = vk ? k : 0;
    float Ej[20];
#pragma unroll
    for (int j = 0; j < 20; j++) Ej[j] = vk ? __expf(trans[j * 20 + k]) : 0.f;
    float eend = vk ? __expf(end_t[kk]) : 0.f;
    float alpha = vk ? (start_t[kk] + em[b * K_ + kk]) : -1e30f;
    float emk = em[(64 + b) * K_ + kk];   // t = 1
    for (int t = 1; t < T_; t++) {
      float em_next = (t < T_ - 1) ? em[((long)(t + 1) * B_ + b) * K_ + kk] : 0.f;
      float m = alpha;
#pragma unroll
      for (int off = 16; off >= 1; off >>= 1) m = fmaxf(m, __shfl_xor(m, off, 32));
      float e = __expf(alpha - m);
      float S = 0.f;
#pragma unroll
      for (int j = 0; j < 20; j++) S = fmaf(__shfl(e, j, 32), Ej[j], S);
      alpha = vk ? (emk + m + __logf(S)) : -1e30f;
      emk = em_next;
    }
    // logZ
    float m = alpha;
#pragma unroll
    for (int off = 16; off >= 1; off >>= 1) m = fmaxf(m, __shfl_xor(m, off, 32));
    float e = __expf(alpha - m) * eend;
#pragma unroll
    for (int off = 16; off >= 1; off >>= 1) e += __shfl_xor(e, off, 32);
    if (lane == 0) atomicAdd(out, m + __logf(e));
  } else {
    // gold-path score: order-free sum, lane l covers t = 8l..8l+7
    int t0 = 8 * lane;
    int tags[9];
#pragma unroll
    for (int i = 0; i < 9; i++) {
      int t = t0 - 1 + i;
      tags[i] = (t >= 0) ? labels[t * B_ + b] : 0;
    }
    float sc = 0.f;
#pragma unroll
    for (int i = 1; i < 9; i++) {
      int t = t0 - 1 + i;
      float v = em[((long)t * B_ + b) * K_ + tags[i]];
      v += (t > 0) ? trans[tags[i - 1] * 20 + tags[i]] : start_t[tags[i]];
      sc += v;
    }
#pragma unroll
    for (int off = 32; off >= 1; off >>= 1) sc += __shfl_xor(sc, off, 64);
    if (lane == 0) {
      sc += end_t[labels[511 * B_ + b]];
      atomicAdd(out, -sc);
    }
  }
}

extern "C" void kernel_launch(void* const* d_in, const int* in_sizes, int n_in,
                              void* d_out, int out_size, void* d_ws, size_t ws_size,
                              hipStream_t stream) {
  const int*   inp     = (const int*)d_in[0];
  const int*   labels  = (const int*)d_in[1];
  const float* emb     = (const float*)d_in[2];
  const float* w_ih    = (const float*)d_in[3];
  const float* w_hh    = (const float*)d_in[4];
  const float* b_ih    = (const float*)d_in[5];
  const float* b_hh    = (const float*)d_in[6];
  const float* W_lin   = (const float*)d_in[7];
  const float* b_lin   = (const float*)d_in[8];
  const float* start_t = (const float*)d_in[9];
  const float* end_t   = (const float*)d_in[10];
  const float* trans   = (const float*)d_in[11];
  float* out = (float*)d_out;
  char* ws = (char*)d_ws;
  (void)ws_size;

  // ws layout (bytes), total ~91.6 MB:
  _Float16*       g_in   = (_Float16*)(ws);                       // 67,108,864 (T*B*1024 f16)
  unsigned short* Xh     = (unsigned short*)(ws + 67108864);      // 20,971,520 (32768x320 bf16)
  _Float16*       houts  = (_Float16*)(ws + 67108864);            // 16,777,216 — ALIASES Xh (Xh dead after kernelA)
  float*          em     = (float*)(ws + 88080384);               //  2,621,440 (T*B*K f32)
  unsigned short* wA     = (unsigned short*)(ws + 90701824);      //    655,360 (10x4x1024x8 bf16)
  signed char*    W8     = (signed char*)(ws + 91357184);         //    262,144 (1024x256 i8)
  float*          b_comb = (float*)(ws + 91619328);               //      4,096

  prep_kernel<<<2048, 256, 0, stream>>>(inp, emb, w_ih, w_hh, b_ih, b_hh, Xh, wA, W8, b_comb, out);
  kernelA<<<4096, 256, 0, stream>>>(Xh, wA, b_comb, g_in);
  kernelB<<<16, 1024, 0, stream>>>(g_in, W8, houts);
  kernelC<<<1024, 256, 0, stream>>>(houts, W_lin, b_lin, em);
  kernelD<<<64, 128, 0, stream>>>(em, labels, start_t, end_t, trans, out);
}

// Round 9
// 782.536 us; speedup vs baseline: 2.3155x; 1.2023x over previous
//
#include <hip/hip_runtime.h>
#include <math.h>

#define T_ 512
#define B_ 64
#define V_ 50000
#define E_ 300
#define H_ 256
#define K_ 20
#define G4 1024  /* 4*H */
#define LOG2E 1.44269504f
#define LN2 0.69314718f

typedef float f4 __attribute__((ext_vector_type(4)));
typedef int v4i __attribute__((ext_vector_type(4)));
typedef short bf16x8 __attribute__((ext_vector_type(8)));
typedef _Float16 h2_t __attribute__((ext_vector_type(2)));
union U32H2 { unsigned u; h2_t h; };
__device__ __forceinline__ h2_t u2h(unsigned u) { U32H2 x; x.u = u; return x.h; }
__device__ __forceinline__ unsigned h2u(h2_t h) { U32H2 x; x.h = h; return x.u; }

__device__ __forceinline__ float rcpf(float x) { return __builtin_amdgcn_rcpf(x); }
__device__ __forceinline__ float exp2f_(float x) { return __builtin_amdgcn_exp2f(x); }

__device__ __forceinline__ unsigned short f32_bf16(float x) {
  union { float f; unsigned u; } v; v.f = x;
  v.u += 0x7FFFu + ((v.u >> 16) & 1u);   // RTNE
  return (unsigned short)(v.u >> 16);
}

#define WSCALE_I 2032.f   /* |w| <= 1/16 -> +-127 */
#define HSCALE_I 127.f    /* |h| < 1    -> +-127 */
#define DESCALE_I (1.f / (WSCALE_I * HSCALE_I))
#define DESCALE2 (DESCALE_I * LOG2E)

// ---- prep: gather X=bf16(emb[inp]) (K padded to 320), pack w_ih A-frags, quantize w_hh i8,
//      combine biases, zero out ------------------------------------------------------------
__global__ void prep_kernel(const int* __restrict__ inp,
                            const float* __restrict__ emb,
                            const float* __restrict__ w_ih, const float* __restrict__ w_hh,
                            const float* __restrict__ b_ih, const float* __restrict__ b_hh,
                            unsigned short* __restrict__ Xh, unsigned short* __restrict__ wA,
                            signed char* __restrict__ W8,
                            float* __restrict__ b_comb, float* __restrict__ out) {
  int tid = blockIdx.x * blockDim.x + threadIdx.x;
  int nth = gridDim.x * blockDim.x;
  for (int i = tid; i < 32768 * 80; i += nth) {
    int row = i / 80, c4 = i % 80, k = c4 * 4;
    ushort4 st;
    if (c4 < 75) {
      int tok = inp[row];
      float4 v = *(const float4*)(emb + (long)tok * E_ + k);
      st.x = f32_bf16(v.x); st.y = f32_bf16(v.y); st.z = f32_bf16(v.z); st.w = f32_bf16(v.w);
    } else {
      st.x = st.y = st.z = st.w = 0;
    }
    *(ushort4*)(Xh + (long)row * 320 + k) = st;
  }
  for (int i = tid; i < 10 * 4 * 1024 * 8; i += nth) {
    int j = i & 7, n = (i >> 3) & 1023, q = (i >> 13) & 3, c = i >> 15;
    int k = c * 32 + q * 8 + j;
    wA[i] = (k < E_) ? f32_bf16(w_ih[n * E_ + k]) : 0;
  }
  // W8[row][k] = i8(round(w_hh[row][k] * 2032)), clamped
  for (int i = tid; i < G4 * H_; i += nth) {
    float v = fminf(fmaxf(w_hh[i] * WSCALE_I, -127.f), 127.f);
    W8[i] = (signed char)__float2int_rn(v);
  }
  for (int i = tid; i < G4; i += nth) b_comb[i] = b_ih[i] + b_hh[i];
  if (tid == 0) out[0] = 0.f;
}

// ---- kernel A: g_in (f16) = (X @ w_ih^T + b) * log2(e), via bf16 MFMA ---------------------
__global__ __launch_bounds__(256) void kernelA(const unsigned short* __restrict__ Xh,
                                               const unsigned short* __restrict__ wA,
                                               const float* __restrict__ b_comb,
                                               _Float16* __restrict__ g_in) {
  __shared__ __align__(16) unsigned short xs[32 * 328];
  int bm = blockIdx.x >> 2, bn = blockIdx.x & 3;
  int tid = threadIdx.x;
  for (int i = tid; i < 32 * 40; i += 256) {
    int r = i / 40, c = i % 40;
    *(uint4*)&xs[r * 328 + c * 8] = *(const uint4*)(Xh + (long)(bm * 32 + r) * 320 + c * 8);
  }
  __syncthreads();
  int lane = tid & 63, w = tid >> 6, col = lane & 15, quad = lane >> 4;
  int nbase = bn * 256 + w * 64;
  f4 acc[2][4];
#pragma unroll
  for (int mt = 0; mt < 2; mt++)
#pragma unroll
    for (int nt = 0; nt < 4; nt++) acc[mt][nt] = (f4){0.f, 0.f, 0.f, 0.f};
#pragma unroll 2
  for (int c = 0; c < 10; c++) {
    bf16x8 a[4], b[2];
#pragma unroll
    for (int nt = 0; nt < 4; nt++)
      a[nt] = *(const bf16x8*)(wA + (((long)c * 4 + quad) * 1024 + nbase + nt * 16 + col) * 8);
#pragma unroll
    for (int mt = 0; mt < 2; mt++)
      b[mt] = *(const bf16x8*)&xs[(mt * 16 + col) * 328 + c * 32 + quad * 8];
#pragma unroll
    for (int mt = 0; mt < 2; mt++)
#pragma unroll
      for (int nt = 0; nt < 4; nt++)
        acc[mt][nt] = __builtin_amdgcn_mfma_f32_16x16x32_bf16(a[nt], b[mt], acc[mt][nt], 0, 0, 0);
  }
#pragma unroll
  for (int mt = 0; mt < 2; mt++) {
    int m = bm * 32 + mt * 16 + col;
#pragma unroll
    for (int nt = 0; nt < 4; nt++) {
      int n = nbase + nt * 16 + quad * 4;
      f4 o = (acc[mt][nt] + *(const f4*)(b_comb + n)) * LOG2E;
      h2_t p0, p1;
      p0.x = (_Float16)o.x; p0.y = (_Float16)o.y;
      p1.x = (_Float16)o.z; p1.y = (_Float16)o.w;
      uint2 st; st.x = h2u(p0); st.y = h2u(p1);
      *(uint2*)(g_in + (long)m * G4 + n) = st;
    }
  }
}

// ---- kernel B v2: sequential LSTM, i8 K=64 MFMA, 32 blocks x 512 thr (8 waves) ------------
// Block bb owns batches {2bb, 2bb+1} (broadcast x8 in 16 cols; cb = col&1).
// Wave w owns units [32w, 32w+32): row-tiles rt(tau, s) = 256*tau + 32w + 16s, 4 K-chunks each
// -> 32 MFMA/wave/step, 8 independent acc chains. Weights = 32 v4i pinned in AGPRs (128 AGPR).
// Lane task: cb=col&1, s=(col>>1)&1, r=col>>2 -> (batch 2bb+cb, unit myk=32w+16s+4quad+r).
// h8 layout (per buf, 512 B): byte (k, cb) at 32*(k>>4) + 16*cb + (k&15).
//   read (chunk c, quad q, batch cb): 16B at 128c + 32q + 16cb  (k = 64c+16q+j)  conflict-free
//   write: myslot = 64w + 32s + 16cb + 4quad + r.
__global__ __launch_bounds__(512, 2) void kernelB(const _Float16* __restrict__ g_in,
                                                  const signed char* __restrict__ W8,
                                                  _Float16* __restrict__ houts) {
  int bb = blockIdx.x;
  int tid = threadIdx.x;
  int lane = tid & 63, w = tid >> 6;
  int col = lane & 15, quad = lane >> 4;
  int cb = col & 1;
  int s = (col >> 1) & 1;
  int r = col >> 2;

  __shared__ __align__(16) signed char h8[2][512];     // [buf][k-major 2 batches x 256]
  __shared__ __align__(16) _Float16 hlin[2][512];      // [buf][cb*256+unit]

  for (int i = tid; i < 2 * 512; i += 512) ((signed char*)h8)[i] = 0;

  // persistent A-frags in AGPRs: wf[(tau*2+sp)*4+c] = W8[(256*tau+32*w+16*sp+col)*256 + 64c + 16*quad ..+15]
  v4i wf[32];
#pragma unroll
  for (int idx = 0; idx < 32; idx++) {
    int tau = idx >> 3, sp = (idx >> 2) & 1, c = idx & 3;
    const signed char* rp = W8 + (unsigned)(256 * tau + 32 * w + 16 * sp + col) * 256 + 64 * c + 16 * quad;
    uint4 q0 = *(const uint4*)rp;
    wf[idx] = (v4i){(int)q0.x, (int)q0.y, (int)q0.z, (int)q0.w};
  }
#pragma unroll
  for (int idx = 0; idx < 32; idx++) asm volatile("" : "+a"(wf[idx]));  // pin in AGPRs

  int myk = 32 * w + 16 * s + 4 * quad + r;     // this lane's hidden unit
  int batch = 2 * bb + cb;                      // this lane's batch
  int myslot = 64 * w + 32 * s + 16 * cb + 4 * quad + r;
  const signed char* bp0 = &h8[0][32 * quad + 16 * cb];
  const signed char* bp1 = &h8[1][32 * quad + 16 * cb];
  const _Float16* gbase = g_in + (long)batch * G4 + myk;

  float cst = 0.f;
  float gi_ = (float)gbase[0];
  float gf_ = (float)gbase[256];
  float gg_ = (float)gbase[512];
  float go_ = (float)gbase[768];
  const _Float16* gp = gbase + (long)B_ * G4;   // running prefetch pointer (t=1)

  __syncthreads();

  for (int t = 0; t < T_; t++) {
    // flush previous step's houts from LDS (coalesced, overlaps this step's MFMAs)
    if (t > 0 && tid < 64) {
      int buf = (t - 1) & 1;
      uint4 v = *(const uint4*)&hlin[buf][tid * 8];
      *(uint4*)(houts + ((long)(t - 1) * B_ + 2 * bb + (tid >> 5)) * H_ + ((tid * 8) & 255)) = v;
    }
    // prefetch next step's g early
    float ngi = (float)gp[0];
    float ngf = (float)gp[256];
    float ngg = (float)gp[512];
    float ngo = (float)gp[768];
    gp += (long)B_ * G4;

    const signed char* bptr = (t & 1) ? bp1 : bp0;
    v4i b0 = *(const v4i*)(bptr);
    v4i b1 = *(const v4i*)(bptr + 128);
    v4i b2 = *(const v4i*)(bptr + 256);
    v4i b3 = *(const v4i*)(bptr + 384);
    v4i acc[8];
#pragma unroll
    for (int i = 0; i < 8; i++) acc[i] = (v4i){0, 0, 0, 0};
#pragma unroll
    for (int i = 0; i < 8; i++) acc[i] = __builtin_amdgcn_mfma_i32_16x16x64_i8(wf[i * 4 + 0], b0, acc[i], 0, 0, 0);
#pragma unroll
    for (int i = 0; i < 8; i++) acc[i] = __builtin_amdgcn_mfma_i32_16x16x64_i8(wf[i * 4 + 1], b1, acc[i], 0, 0, 0);
#pragma unroll
    for (int i = 0; i < 8; i++) acc[i] = __builtin_amdgcn_mfma_i32_16x16x64_i8(wf[i * 4 + 2], b2, acc[i], 0, 0, 0);
#pragma unroll
    for (int i = 0; i < 8; i++) acc[i] = __builtin_amdgcn_mfma_i32_16x16x64_i8(wf[i * 4 + 3], b3, acc[i], 0, 0, 0);

    // extract this lane's 4 gate values: gate tau -> acc[2*tau + s][r]
    v4i g0v = s ? acc[1] : acc[0];
    v4i g1v = s ? acc[3] : acc[2];
    v4i g2v = s ? acc[5] : acc[4];
    v4i g3v = s ? acc[7] : acc[6];
    float gi = (float)g0v[r] * DESCALE2 + gi_;
    float gf = (float)g1v[r] * DESCALE2 + gf_;
    float gg = (float)g2v[r] * DESCALE2 + gg_;
    float go = (float)g3v[r] * DESCALE2 + go_;
    float si = rcpf(1.f + exp2f_(-gi));
    float sf = rcpf(1.f + exp2f_(-gf));
    float so = rcpf(1.f + exp2f_(-go));
    float tg = 1.f - 2.f * rcpf(1.f + exp2f_(gg + gg));            // tanh(gg_real)
    cst = sf * cst + si * tg;
    float tc_ = 1.f - 2.f * rcpf(1.f + exp2f_(2.88539008f * cst)); // tanh(cst)
    float h = so * tc_;
    h8[1 - (t & 1)][myslot] = (signed char)__float2int_rn(h * HSCALE_I);
    hlin[t & 1][cb * 256 + myk] = (_Float16)h;

    gi_ = ngi; gf_ = ngf; gg_ = ngg; go_ = ngo;
    __syncthreads();
  }
  // final flush: step 511 lives in buf 1
  if (tid < 64) {
    uint4 v = *(const uint4*)&hlin[1][tid * 8];
    *(uint4*)(houts + ((long)511 * B_ + 2 * bb + (tid >> 5)) * H_ + ((tid * 8) & 255)) = v;
  }
}

// ---- kernel C: emissions = houts(f16) @ W_lin^T + b_lin -----------------------------------
__global__ __launch_bounds__(256) void kernelC(const _Float16* __restrict__ houts,
                                               const float* __restrict__ W_lin,
                                               const float* __restrict__ b_lin,
                                               float* __restrict__ em) {
  __shared__ float hs[32][260];
  __shared__ float wl[20][260];
  __shared__ float bl[20];
  int bm = blockIdx.x;
  int tid = threadIdx.x;
  for (int i = tid; i < 32 * 64; i += 256) {
    int r = i >> 6, c = i & 63;
    uint2 v = *(const uint2*)(houts + ((long)(bm * 32 + r)) * H_ + c * 4);
    h2_t h0 = u2h(v.x), h1 = u2h(v.y);
    *(float4*)&hs[r][c * 4] = make_float4((float)h0.x, (float)h0.y, (float)h1.x, (float)h1.y);
  }
  for (int i = tid; i < 20 * 64; i += 256) {
    int k = i >> 6, c = i & 63;
    *(float4*)&wl[k][c * 4] = *(const float4*)(W_lin + k * H_ + c * 4);
  }
  if (tid < 20) bl[tid] = b_lin[tid];
  __syncthreads();
  for (int o = tid; o < 32 * 20; o += 256) {
    int r = o / 20, k = o % 20;
    float s = 0.f;
#pragma unroll 4
    for (int i = 0; i < H_; i++) s += hs[r][i] * wl[k][i];
    em[(long)bm * 32 * K_ + o] = s + bl[k];
  }
}

// ---- kernel D: CRF. wave0: rel-log2-domain forward DP (no max tree); wave1: gold score. ----
__global__ __launch_bounds__(128) void kernelD(const float* __restrict__ em,
                                               const int* __restrict__ labels,
                                               const float* __restrict__ start_t,
                                               const float* __restrict__ end_t,
                                               const float* __restrict__ trans,
                                               float* __restrict__ out) {
  int b = blockIdx.x;
  int tid = threadIdx.x;
  int lane = tid & 63;
  int wv = tid >> 6;
  if (wv == 0) {
    int k = lane & 31;
    bool vk = (k < K_);
    int kk = vk ? k : 0;
    float E[20];   // linear-domain exp(trans[j][k])
#pragma unroll
    for (int j = 0; j < 20; j++) E[j] = vk ? __expf(trans[j * 20 + k]) : 0.f;
    float end2 = vk ? end_t[kk] * LOG2E : -1e30f;
    // a2: log2-domain alpha relative to lane 0 (lane-0 value always 0 -> exp2 range bounded)
    float raw0 = (start_t[kk] + em[b * K_ + kk]) * LOG2E;
    float D2 = __shfl(raw0, 0, 32);
    float a2 = vk ? (raw0 - D2) : -1e30f;
    float C2 = D2;
    float emk = em[(64 + b) * K_ + kk];   // t = 1
    for (int t = 1; t < T_; t++) {
      float em_next = (t < T_ - 1) ? em[((long)(t + 1) * B_ + b) * K_ + kk] : 0.f;
      float e = exp2f_(a2);              // invalid lanes: exp2(-1e30) = 0
      float S = 0.f;
#pragma unroll
      for (int j = 0; j < 20; j++) S = fmaf(__shfl(e, j, 32), E[j], S);
      float raw = emk * LOG2E + __log2f(S);
      float Dn = __shfl(raw, 0, 32);
      a2 = vk ? (raw - Dn) : -1e30f;
      C2 += Dn;
      emk = em_next;
    }
    // logZ = ln2 * (C2 + log2(sum exp2(a2 + end2)))
    float fin = vk ? (a2 + end2) : -1e30f;
    float m = fin;
#pragma unroll
    for (int off = 16; off >= 1; off >>= 1) m = fmaxf(m, __shfl_xor(m, off, 32));
    float e = vk ? exp2f_(fin - m) : 0.f;
#pragma unroll
    for (int off = 16; off >= 1; off >>= 1) e += __shfl_xor(e, off, 32);
    if (lane == 0) atomicAdd(out, LN2 * (C2 + m + __log2f(e)));
  } else {
    // gold-path score: order-free sum, lane l covers t = 8l..8l+7
    int t0 = 8 * lane;
    int tags[9];
#pragma unroll
    for (int i = 0; i < 9; i++) {
      int t = t0 - 1 + i;
      tags[i] = (t >= 0) ? labels[t * B_ + b] : 0;
    }
    float sc = 0.f;
#pragma unroll
    for (int i = 1; i < 9; i++) {
      int t = t0 - 1 + i;
      float v = em[((long)t * B_ + b) * K_ + tags[i]];
      v += (t > 0) ? trans[tags[i - 1] * 20 + tags[i]] : start_t[tags[i]];
      sc += v;
    }
#pragma unroll
    for (int off = 32; off >= 1; off >>= 1) sc += __shfl_xor(sc, off, 64);
    if (lane == 0) {
      sc += end_t[labels[511 * B_ + b]];
      atomicAdd(out, -sc);
    }
  }
}

extern "C" void kernel_launch(void* const* d_in, const int* in_sizes, int n_in,
                              void* d_out, int out_size, void* d_ws, size_t ws_size,
                              hipStream_t stream) {
  const int*   inp     = (const int*)d_in[0];
  const int*   labels  = (const int*)d_in[1];
  const float* emb     = (const float*)d_in[2];
  const float* w_ih    = (const float*)d_in[3];
  const float* w_hh    = (const float*)d_in[4];
  const float* b_ih    = (const float*)d_in[5];
  const float* b_hh    = (const float*)d_in[6];
  const float* W_lin   = (const float*)d_in[7];
  const float* b_lin   = (const float*)d_in[8];
  const float* start_t = (const float*)d_in[9];
  const float* end_t   = (const float*)d_in[10];
  const float* trans   = (const float*)d_in[11];
  float* out = (float*)d_out;
  char* ws = (char*)d_ws;
  (void)ws_size;

  // ws layout (bytes), total ~91.6 MB:
  _Float16*       g_in   = (_Float16*)(ws);                       // 67,108,864 (T*B*1024 f16)
  unsigned short* Xh     = (unsigned short*)(ws + 67108864);      // 20,971,520 (32768x320 bf16)
  _Float16*       houts  = (_Float16*)(ws + 67108864);            // 16,777,216 — ALIASES Xh (Xh dead after kernelA)
  float*          em     = (float*)(ws + 88080384);               //  2,621,440 (T*B*K f32)
  unsigned short* wA     = (unsigned short*)(ws + 90701824);      //    655,360 (10x4x1024x8 bf16)
  signed char*    W8     = (signed char*)(ws + 91357184);         //    262,144 (1024x256 i8)
  float*          b_comb = (float*)(ws + 91619328);               //      4,096

  prep_kernel<<<2048, 256, 0, stream>>>(inp, emb, w_ih, w_hh, b_ih, b_hh, Xh, wA, W8, b_comb, out);
  kernelA<<<4096, 256, 0, stream>>>(Xh, wA, b_comb, g_in);
  kernelB<<<32, 512, 0, stream>>>(g_in, W8, houts);
  kernelC<<<1024, 256, 0, stream>>>(houts, W_lin, b_lin, em);
  kernelD<<<64, 128, 0, stream>>>(em, labels, start_t, end_t, trans, out);
}

// Round 10
// 726.235 us; speedup vs baseline: 2.4950x; 1.0775x over previous
//
#include <hip/hip_runtime.h>
#include <math.h>

#define T_ 512
#define B_ 64
#define V_ 50000
#define E_ 300
#define H_ 256
#define K_ 20
#define G4 1024  /* 4*H */
#define LOG2E 1.44269504f
#define LN2 0.69314718f

typedef float f4 __attribute__((ext_vector_type(4)));
typedef int v8i __attribute__((ext_vector_type(8)));
typedef short bf16x8 __attribute__((ext_vector_type(8)));
typedef _Float16 h2_t __attribute__((ext_vector_type(2)));
union U32H2 { unsigned u; h2_t h; };
__device__ __forceinline__ h2_t u2h(unsigned u) { U32H2 x; x.u = u; return x.h; }
__device__ __forceinline__ unsigned h2u(h2_t h) { U32H2 x; x.h = h; return x.u; }

__device__ __forceinline__ float rcpf(float x) { return __builtin_amdgcn_rcpf(x); }
__device__ __forceinline__ float exp2f_(float x) { return __builtin_amdgcn_exp2f(x); }

__device__ __forceinline__ unsigned char f32_e4m3(float x) {
  return (unsigned char)(__builtin_amdgcn_cvt_pk_fp8_f32(x, x, 0, false) & 0xff);
}
__device__ __forceinline__ unsigned short f32_bf16(float x) {
  union { float f; unsigned u; } v; v.f = x;
  v.u += 0x7FFFu + ((v.u >> 16) & 1u);   // RTNE
  return (unsigned short)(v.u >> 16);
}

#define WSCALE 64.f      /* fp8 e4m3 weight scale (R4/R5-proven) */
#define HSCALE 16.f      /* fp8 e4m3 h scale */
#define DESCALE2 (LOG2E / (WSCALE * HSCALE))
#define SC1 0x7F7F7F7F   /* e8m0 exponent 127 = scale 1.0 */

// ---- prep: gather X=bf16(emb[inp]) (K padded to 320), pack w_ih A-frags, quantize w_hh fp8,
//      combine biases, zero out ------------------------------------------------------------
__global__ void prep_kernel(const int* __restrict__ inp,
                            const float* __restrict__ emb,
                            const float* __restrict__ w_ih, const float* __restrict__ w_hh,
                            const float* __restrict__ b_ih, const float* __restrict__ b_hh,
                            unsigned short* __restrict__ Xh, unsigned short* __restrict__ wA,
                            unsigned char* __restrict__ W8,
                            float* __restrict__ b_comb, float* __restrict__ out) {
  int tid = blockIdx.x * blockDim.x + threadIdx.x;
  int nth = gridDim.x * blockDim.x;
  for (int i = tid; i < 32768 * 80; i += nth) {
    int row = i / 80, c4 = i % 80, k = c4 * 4;
    ushort4 st;
    if (c4 < 75) {
      int tok = inp[row];
      float4 v = *(const float4*)(emb + (long)tok * E_ + k);
      st.x = f32_bf16(v.x); st.y = f32_bf16(v.y); st.z = f32_bf16(v.z); st.w = f32_bf16(v.w);
    } else {
      st.x = st.y = st.z = st.w = 0;
    }
    *(ushort4*)(Xh + (long)row * 320 + k) = st;
  }
  for (int i = tid; i < 10 * 4 * 1024 * 8; i += nth) {
    int j = i & 7, n = (i >> 3) & 1023, q = (i >> 13) & 3, c = i >> 15;
    int k = c * 32 + q * 8 + j;
    wA[i] = (k < E_) ? f32_bf16(w_ih[n * E_ + k]) : 0;
  }
  // W8[row][k] = e4m3(w_hh[row][k] * 64)
  for (int i = tid; i < G4 * H_; i += nth) W8[i] = f32_e4m3(w_hh[i] * WSCALE);
  for (int i = tid; i < G4; i += nth) b_comb[i] = b_ih[i] + b_hh[i];
  if (tid == 0) out[0] = 0.f;
}

// ---- kernel A: g_in (f16) = (X @ w_ih^T + b) * log2(e), via bf16 MFMA ---------------------
__global__ __launch_bounds__(256) void kernelA(const unsigned short* __restrict__ Xh,
                                               const unsigned short* __restrict__ wA,
                                               const float* __restrict__ b_comb,
                                               _Float16* __restrict__ g_in) {
  __shared__ __align__(16) unsigned short xs[32 * 328];
  int bm = blockIdx.x >> 2, bn = blockIdx.x & 3;
  int tid = threadIdx.x;
  for (int i = tid; i < 32 * 40; i += 256) {
    int r = i / 40, c = i % 40;
    *(uint4*)&xs[r * 328 + c * 8] = *(const uint4*)(Xh + (long)(bm * 32 + r) * 320 + c * 8);
  }
  __syncthreads();
  int lane = tid & 63, w = tid >> 6, col = lane & 15, quad = lane >> 4;
  int nbase = bn * 256 + w * 64;
  f4 acc[2][4];
#pragma unroll
  for (int mt = 0; mt < 2; mt++)
#pragma unroll
    for (int nt = 0; nt < 4; nt++) acc[mt][nt] = (f4){0.f, 0.f, 0.f, 0.f};
#pragma unroll 2
  for (int c = 0; c < 10; c++) {
    bf16x8 a[4], b[2];
#pragma unroll
    for (int nt = 0; nt < 4; nt++)
      a[nt] = *(const bf16x8*)(wA + (((long)c * 4 + quad) * 1024 + nbase + nt * 16 + col) * 8);
#pragma unroll
    for (int mt = 0; mt < 2; mt++)
      b[mt] = *(const bf16x8*)&xs[(mt * 16 + col) * 328 + c * 32 + quad * 8];
#pragma unroll
    for (int mt = 0; mt < 2; mt++)
#pragma unroll
      for (int nt = 0; nt < 4; nt++)
        acc[mt][nt] = __builtin_amdgcn_mfma_f32_16x16x32_bf16(a[nt], b[mt], acc[mt][nt], 0, 0, 0);
  }
#pragma unroll
  for (int mt = 0; mt < 2; mt++) {
    int m = bm * 32 + mt * 16 + col;
#pragma unroll
    for (int nt = 0; nt < 4; nt++) {
      int n = nbase + nt * 16 + quad * 4;
      f4 o = (acc[mt][nt] + *(const f4*)(b_comb + n)) * LOG2E;
      h2_t p0, p1;
      p0.x = (_Float16)o.x; p0.y = (_Float16)o.y;
      p1.x = (_Float16)o.z; p1.y = (_Float16)o.w;
      uint2 st; st.x = h2u(p0); st.y = h2u(p1);
      *(uint2*)(g_in + (long)m * G4 + n) = st;
    }
  }
}

// ---- kernel B v3: sequential LSTM, MX-fp8 K=128 MFMA, weights pinned in VGPRs -------------
// 32 blocks x 512 thr (8 waves); block bb owns batches {2bb, 2bb+1} (cb = col&1, x8 bcast).
// Wave w owns units [32w, 32w+32): tiles rt(tau,s) = 256*tau + 32w + 16s, 2 K=128 chunks each
// -> 16 MFMA/wave/step (8 indep chains). A-frags = 16 x v8i = 128 VGPRs, "+v"-pinned (cap 256
// at __launch_bounds__(512,2); R5's scaled-MFMA slowdown was the 1024-thr 128-reg cap).
// h8 k-linear per batch (R5-proven K=128 B layout): byte (cb, k) at cb*272 + k;
//   read (chunk c, quad q): 32B at cb*272 + 128c + 32q -> 2 bcast addrs/quarter-wave (free).
__global__ __launch_bounds__(512, 2) void kernelB(const _Float16* __restrict__ g_in,
                                                  const unsigned char* __restrict__ W8,
                                                  _Float16* __restrict__ houts) {
  int bb = blockIdx.x;
  int tid = threadIdx.x;
  int lane = tid & 63, w = tid >> 6;
  int col = lane & 15, quad = lane >> 4;
  int cb = col & 1;
  int s = (col >> 1) & 1;
  int r = col >> 2;

  __shared__ __align__(16) unsigned char h8[2][544];   // [buf][cb*272 + k], k linear
  __shared__ __align__(16) _Float16 hlin[2][512];      // [buf][cb*256+unit]

  for (int i = tid; i < 2 * 544; i += 512) ((unsigned char*)h8)[i] = 0;

  // persistent A-frags in VGPRs: wfv[(tau*2+s)*2+c] = W8[(256*tau+32*w+16*s+col)*256 + 128c + 32*quad ..+31]
  v8i wfv[16];
#pragma unroll
  for (int idx = 0; idx < 16; idx++) {
    int tau = idx >> 2, sp = (idx >> 1) & 1, c = idx & 1;
    const unsigned char* rp = W8 + (unsigned)(256 * tau + 32 * w + 16 * sp + col) * 256 + 128 * c + 32 * quad;
    uint4 q0 = *(const uint4*)rp;
    uint4 q1 = *(const uint4*)(rp + 16);
    wfv[idx] = (v8i){(int)q0.x, (int)q0.y, (int)q0.z, (int)q0.w,
                     (int)q1.x, (int)q1.y, (int)q1.z, (int)q1.w};
  }
#pragma unroll
  for (int idx = 0; idx < 16; idx++) asm volatile("" : "+v"(wfv[idx]));  // pin: no remat, no AGPR copies

  f4 zero4 = {0.f, 0.f, 0.f, 0.f};
  asm volatile("" : "+v"(zero4));               // shared C=0 operand: kills per-step acc-init movs

  int myk = 32 * w + 16 * s + 4 * quad + r;     // this lane's hidden unit
  int batch = 2 * bb + cb;                      // this lane's batch
  int myslot = cb * 272 + myk;                  // linear h8 slot
  const unsigned char* bp0 = &h8[0][cb * 272 + 32 * quad];
  const unsigned char* bp1 = &h8[1][cb * 272 + 32 * quad];
  const _Float16* gbase = g_in + (long)batch * G4 + myk;

  float cst = 0.f;
  float gi_ = (float)gbase[0];
  float gf_ = (float)gbase[256];
  float gg_ = (float)gbase[512];
  float go_ = (float)gbase[768];
  const _Float16* gp = gbase + (long)B_ * G4;   // running prefetch pointer (t=1)

  __syncthreads();

#pragma unroll 2
  for (int t = 0; t < T_; t++) {
    // flush previous step's houts from LDS (coalesced, overlaps this step's MFMAs)
    if (t > 0 && tid < 64) {
      int buf = (t - 1) & 1;
      uint4 v = *(const uint4*)&hlin[buf][tid * 8];
      *(uint4*)(houts + ((long)(t - 1) * B_ + 2 * bb + (tid >> 5)) * H_ + ((tid * 8) & 255)) = v;
    }
    // prefetch next step's g early
    float ngi = (float)gp[0];
    float ngf = (float)gp[256];
    float ngg = (float)gp[512];
    float ngo = (float)gp[768];
    gp += (long)B_ * G4;

    const unsigned char* bptr = (t & 1) ? bp1 : bp0;
    v8i b0, b1;
    {
      uint4 q0 = *(const uint4*)(bptr);
      uint4 q1 = *(const uint4*)(bptr + 16);
      uint4 q2 = *(const uint4*)(bptr + 128);
      uint4 q3 = *(const uint4*)(bptr + 144);
      b0 = (v8i){(int)q0.x, (int)q0.y, (int)q0.z, (int)q0.w,
                 (int)q1.x, (int)q1.y, (int)q1.z, (int)q1.w};
      b1 = (v8i){(int)q2.x, (int)q2.y, (int)q2.z, (int)q2.w,
                 (int)q3.x, (int)q3.y, (int)q3.z, (int)q3.w};
    }
    f4 acc[8];
#pragma unroll
    for (int i = 0; i < 8; i++)
      acc[i] = __builtin_amdgcn_mfma_scale_f32_16x16x128_f8f6f4(wfv[i * 2 + 0], b0, zero4, 0, 0, 0, SC1, 0, SC1);
#pragma unroll
    for (int i = 0; i < 8; i++)
      acc[i] = __builtin_amdgcn_mfma_scale_f32_16x16x128_f8f6f4(wfv[i * 2 + 1], b1, acc[i], 0, 0, 0, SC1, 0, SC1);

    // extract this lane's 4 gate values: gate tau -> acc[2*tau + s][r]
    f4 g0v = s ? acc[1] : acc[0];
    f4 g1v = s ? acc[3] : acc[2];
    f4 g2v = s ? acc[5] : acc[4];
    f4 g3v = s ? acc[7] : acc[6];
    float gi = g0v[r] * DESCALE2 + gi_;
    float gf = g1v[r] * DESCALE2 + gf_;
    float gg = g2v[r] * DESCALE2 + gg_;
    float go = g3v[r] * DESCALE2 + go_;
    float si = rcpf(1.f + exp2f_(-gi));
    float sf = rcpf(1.f + exp2f_(-gf));
    float so = rcpf(1.f + exp2f_(-go));
    float tg = 1.f - 2.f * rcpf(1.f + exp2f_(gg + gg));            // tanh(gg_real)
    cst = sf * cst + si * tg;
    float tc_ = 1.f - 2.f * rcpf(1.f + exp2f_(2.88539008f * cst)); // tanh(cst)
    float h = so * tc_;
    h8[1 - (t & 1)][myslot] = f32_e4m3(h * HSCALE);
    hlin[t & 1][cb * 256 + myk] = (_Float16)h;

    gi_ = ngi; gf_ = ngf; gg_ = ngg; go_ = ngo;
    __syncthreads();
  }
  // final flush: step 511 lives in buf 1
  if (tid < 64) {
    uint4 v = *(const uint4*)&hlin[1][tid * 8];
    *(uint4*)(houts + ((long)511 * B_ + 2 * bb + (tid >> 5)) * H_ + ((tid * 8) & 255)) = v;
  }
}

// ---- kernel C: emissions = houts(f16) @ W_lin^T + b_lin -----------------------------------
__global__ __launch_bounds__(256) void kernelC(const _Float16* __restrict__ houts,
                                               const float* __restrict__ W_lin,
                                               const float* __restrict__ b_lin,
                                               float* __restrict__ em) {
  __shared__ float hs[32][260];
  __shared__ float wl[20][260];
  __shared__ float bl[20];
  int bm = blockIdx.x;
  int tid = threadIdx.x;
  for (int i = tid; i < 32 * 64; i += 256) {
    int r = i >> 6, c = i & 63;
    uint2 v = *(const uint2*)(houts + ((long)(bm * 32 + r)) * H_ + c * 4);
    h2_t h0 = u2h(v.x), h1 = u2h(v.y);
    *(float4*)&hs[r][c * 4] = make_float4((float)h0.x, (float)h0.y, (float)h1.x, (float)h1.y);
  }
  for (int i = tid; i < 20 * 64; i += 256) {
    int k = i >> 6, c = i & 63;
    *(float4*)&wl[k][c * 4] = *(const float4*)(W_lin + k * H_ + c * 4);
  }
  if (tid < 20) bl[tid] = b_lin[tid];
  __syncthreads();
  for (int o = tid; o < 32 * 20; o += 256) {
    int r = o / 20, k = o % 20;
    float s = 0.f;
#pragma unroll 4
    for (int i = 0; i < H_; i++) s += hs[r][i] * wl[k][i];
    em[(long)bm * 32 * K_ + o] = s + bl[k];
  }
}

// ---- kernel D: CRF. wave0: rel-log2-domain forward DP (no max tree); wave1: gold score. ----
__global__ __launch_bounds__(128) void kernelD(const float* __restrict__ em,
                                               const int* __restrict__ labels,
                                               const float* __restrict__ start_t,
                                               const float* __restrict__ end_t,
                                               const float* __restrict__ trans,
                                               float* __restrict__ out) {
  int b = blockIdx.x;
  int tid = threadIdx.x;
  int lane = tid & 63;
  int wv = tid >> 6;
  if (wv == 0) {
    int k = lane & 31;
    bool vk = (k < K_);
    int kk = vk ? k : 0;
    float E[20];   // linear-domain exp(trans[j][k])
#pragma unroll
    for (int j = 0; j < 20; j++) E[j] = vk ? __expf(trans[j * 20 + k]) : 0.f;
    float end2 = vk ? end_t[kk] * LOG2E : -1e30f;
    float raw0 = (start_t[kk] + em[b * K_ + kk]) * LOG2E;
    float D2 = __shfl(raw0, 0, 32);
    float a2 = vk ? (raw0 - D2) : -1e30f;
    float C2 = D2;
    float emk = em[(64 + b) * K_ + kk];   // t = 1
    for (int t = 1; t < T_; t++) {
      float em_next = (t < T_ - 1) ? em[((long)(t + 1) * B_ + b) * K_ + kk] : 0.f;
      float e = exp2f_(a2);              // invalid lanes: exp2(-1e30) = 0
      float S = 0.f;
#pragma unroll
      for (int j = 0; j < 20; j++) S = fmaf(__shfl(e, j, 32), E[j], S);
      float raw = emk * LOG2E + __log2f(S);
      float Dn = __shfl(raw, 0, 32);
      a2 = vk ? (raw - Dn) : -1e30f;
      C2 += Dn;
      emk = em_next;
    }
    float fin = vk ? (a2 + end2) : -1e30f;
    float m = fin;
#pragma unroll
    for (int off = 16; off >= 1; off >>= 1) m = fmaxf(m, __shfl_xor(m, off, 32));
    float e = vk ? exp2f_(fin - m) : 0.f;
#pragma unroll
    for (int off = 16; off >= 1; off >>= 1) e += __shfl_xor(e, off, 32);
    if (lane == 0) atomicAdd(out, LN2 * (C2 + m + __log2f(e)));
  } else {
    // gold-path score: order-free sum, lane l covers t = 8l..8l+7
    int t0 = 8 * lane;
    int tags[9];
#pragma unroll
    for (int i = 0; i < 9; i++) {
      int t = t0 - 1 + i;
      tags[i] = (t >= 0) ? labels[t * B_ + b] : 0;
    }
    float sc = 0.f;
#pragma unroll
    for (int i = 1; i < 9; i++) {
      int t = t0 - 1 + i;
      float v = em[((long)t * B_ + b) * K_ + tags[i]];
      v += (t > 0) ? trans[tags[i - 1] * 20 + tags[i]] : start_t[tags[i]];
      sc += v;
    }
#pragma unroll
    for (int off = 32; off >= 1; off >>= 1) sc += __shfl_xor(sc, off, 64);
    if (lane == 0) {
      sc += end_t[labels[511 * B_ + b]];
      atomicAdd(out, -sc);
    }
  }
}

extern "C" void kernel_launch(void* const* d_in, const int* in_sizes, int n_in,
                              void* d_out, int out_size, void* d_ws, size_t ws_size,
                              hipStream_t stream) {
  const int*   inp     = (const int*)d_in[0];
  const int*   labels  = (const int*)d_in[1];
  const float* emb     = (const float*)d_in[2];
  const float* w_ih    = (const float*)d_in[3];
  const float* w_hh    = (const float*)d_in[4];
  const float* b_ih    = (const float*)d_in[5];
  const float* b_hh    = (const float*)d_in[6];
  const float* W_lin   = (const float*)d_in[7];
  const float* b_lin   = (const float*)d_in[8];
  const float* start_t = (const float*)d_in[9];
  const float* end_t   = (const float*)d_in[10];
  const float* trans   = (const float*)d_in[11];
  float* out = (float*)d_out;
  char* ws = (char*)d_ws;
  (void)ws_size;

  // ws layout (bytes), total ~91.6 MB:
  _Float16*       g_in   = (_Float16*)(ws);                       // 67,108,864 (T*B*1024 f16)
  unsigned short* Xh     = (unsigned short*)(ws + 67108864);      // 20,971,520 (32768x320 bf16)
  _Float16*       houts  = (_Float16*)(ws + 67108864);            // 16,777,216 — ALIASES Xh (Xh dead after kernelA)
  float*          em     = (float*)(ws + 88080384);               //  2,621,440 (T*B*K f32)
  unsigned short* wA     = (unsigned short*)(ws + 90701824);      //    655,360 (10x4x1024x8 bf16)
  unsigned char*  W8     = (unsigned char*)(ws + 91357184);       //    262,144 (1024x256 fp8)
  float*          b_comb = (float*)(ws + 91619328);               //      4,096

  prep_kernel<<<2048, 256, 0, stream>>>(inp, emb, w_ih, w_hh, b_ih, b_hh, Xh, wA, W8, b_comb, out);
  kernelA<<<4096, 256, 0, stream>>>(Xh, wA, b_comb, g_in);
  kernelB<<<32, 512, 0, stream>>>(g_in, W8, houts);
  kernelC<<<1024, 256, 0, stream>>>(houts, W_lin, b_lin, em);
  kernelD<<<64, 128, 0, stream>>>(em, labels, start_t, end_t, trans, out);
}